// Round 1
// baseline (1179.519 us; speedup 1.0000x reference)
//
#include <hip/hip_runtime.h>

#define N_NODES 50000
#define N_EDGES 800000
#define N_GRAPHS 500
#define DH 128
#define OUT_STRIDE 384
#define BN_EPS 1e-5f

__device__ __forceinline__ float4 ld4(const float* p) { return *(const float4*)p; }
__device__ __forceinline__ void st4(float* p, float4 v) { *(float4*)p = v; }

// ---------------- CSR build ----------------
__global__ void count_deg_k(const int* __restrict__ dst, int* __restrict__ deg, int E) {
    int e = blockIdx.x * 256 + threadIdx.x;
    if (e < E) atomicAdd(&deg[dst[e]], 1);
}

__global__ void scan_deg_k(const int* __restrict__ deg, int* __restrict__ rowstart,
                           int* __restrict__ cursor, int n) {
    __shared__ int part[1024];
    int t = threadIdx.x;
    int chunk = (n + 1023) >> 10;
    int i0 = t * chunk, i1 = min(i0 + chunk, n);
    int s = 0;
    for (int i = i0; i < i1; ++i) s += deg[i];
    part[t] = s;
    __syncthreads();
    for (int off = 1; off < 1024; off <<= 1) {
        int v = (t >= off) ? part[t - off] : 0;
        __syncthreads();
        part[t] += v;
        __syncthreads();
    }
    int base = part[t] - s;  // exclusive prefix
    for (int i = i0; i < i1; ++i) {
        int d = deg[i];
        rowstart[i] = base;
        cursor[i] = base;
        base += d;
    }
    if (t == 1023) rowstart[n] = part[1023];
}

__global__ void csr_fill_k(const int* __restrict__ src, const int* __restrict__ dst,
                           const float* __restrict__ ea, int* __restrict__ cursor,
                           int* __restrict__ adj_src, float* __restrict__ adj_ea, int E) {
    int e = blockIdx.x * 256 + threadIdx.x;
    if (e >= E) return;
    int pos = atomicAdd(&cursor[dst[e]], 1);
    adj_src[pos] = src[e];
    adj_ea[pos * 3 + 0] = ea[e * 3 + 0];
    adj_ea[pos * 3 + 1] = ea[e * 3 + 1];
    adj_ea[pos * 3 + 2] = ea[e * 3 + 2];
}

// ---------------- small transpose: in[R][C] -> out[C][R] ----------------
__global__ void transpose_k(const float* __restrict__ in, float* __restrict__ out, int R, int C) {
    int idx = blockIdx.x * 256 + threadIdx.x;
    if (idx < R * C) {
        int r = idx / C, c = idx - r * C;
        out[c * R + r] = in[idx];
    }
}

// ---------------- aggregation: y = x + sum_{e:dst=i} relu(x[src]+Lin(ea)) ----------------
__global__ __launch_bounds__(256) void agg_d9_k(
    const float* __restrict__ x, const int* __restrict__ rowstart,
    const int* __restrict__ adj_src, const float* __restrict__ adj_ea,
    const float* __restrict__ We /*[9][3]*/, const float* __restrict__ be,
    float* __restrict__ y, int n) {
    int i = blockIdx.x * 256 + threadIdx.x;
    if (i >= n) return;
    float w0[9], w1[9], w2[9], bb[9], acc[9];
#pragma unroll
    for (int j = 0; j < 9; ++j) {
        w0[j] = We[j * 3 + 0];
        w1[j] = We[j * 3 + 1];
        w2[j] = We[j * 3 + 2];
        bb[j] = be[j];
        acc[j] = x[(size_t)i * 9 + j];
    }
    int k1 = rowstart[i + 1];
    for (int k = rowstart[i]; k < k1; ++k) {
        int s = adj_src[k];
        float e0 = adj_ea[k * 3 + 0], e1 = adj_ea[k * 3 + 1], e2 = adj_ea[k * 3 + 2];
#pragma unroll
        for (int j = 0; j < 9; ++j) {
            float lin = fmaf(w0[j], e0, fmaf(w1[j], e1, fmaf(w2[j], e2, bb[j])));
            acc[j] += fmaxf(x[(size_t)s * 9 + j] + lin, 0.f);
        }
    }
#pragma unroll
    for (int j = 0; j < 9; ++j) y[(size_t)i * 9 + j] = acc[j];
}

__global__ __launch_bounds__(256) void agg_d128_k(
    const float* __restrict__ h, const int* __restrict__ rowstart,
    const int* __restrict__ adj_src, const float* __restrict__ adj_ea,
    const float* __restrict__ WeT /*[3][128]*/, const float* __restrict__ be,
    float* __restrict__ y, int n) {
    int lane = threadIdx.x & 31;
    int node = blockIdx.x * 8 + (threadIdx.x >> 5);
    if (node >= n) return;
    int c = lane * 4;
    float4 w0 = ld4(&WeT[0 * 128 + c]);
    float4 w1 = ld4(&WeT[1 * 128 + c]);
    float4 w2 = ld4(&WeT[2 * 128 + c]);
    float4 b4 = ld4(&be[c]);
    float4 acc = ld4(&h[(size_t)node * 128 + c]);
    int k1 = rowstart[node + 1];
    for (int k = rowstart[node]; k < k1; ++k) {
        int s = adj_src[k];
        float e0 = adj_ea[k * 3 + 0], e1 = adj_ea[k * 3 + 1], e2 = adj_ea[k * 3 + 2];
        float4 xe = ld4(&h[(size_t)s * 128 + c]);
        float mx = fmaf(w0.x, e0, fmaf(w1.x, e1, fmaf(w2.x, e2, b4.x))) + xe.x;
        float my = fmaf(w0.y, e0, fmaf(w1.y, e1, fmaf(w2.y, e2, b4.y))) + xe.y;
        float mz = fmaf(w0.z, e0, fmaf(w1.z, e1, fmaf(w2.z, e2, b4.z))) + xe.z;
        float mw = fmaf(w0.w, e0, fmaf(w1.w, e1, fmaf(w2.w, e2, b4.w))) + xe.w;
        acc.x += fmaxf(mx, 0.f);
        acc.y += fmaxf(my, 0.f);
        acc.z += fmaxf(mz, 0.f);
        acc.w += fmaxf(mw, 0.f);
    }
    st4(&y[(size_t)node * 128 + c], acc);
}

// ---------------- GEMM1 (y @ W1^T) + BN column stats ----------------
template <int DIN, int KC>
__global__ __launch_bounds__(256) void gemm1_stats_k(
    const float* __restrict__ Yin, const float* __restrict__ WT /*[DIN][128]*/,
    float* __restrict__ Hout, float* __restrict__ col_sum, float* __restrict__ col_sumsq, int n) {
    __shared__ __align__(16) float Ylds[64 * DIN];
    __shared__ __align__(16) float Wlds[KC * 128];
    __shared__ __align__(16) float red[8 * 128];
    const int t = threadIdx.x;
    const int row0 = blockIdx.x * 64;

    if constexpr (DIN % 4 == 0) {
        const int nv = 64 * DIN / 4;
        for (int i4 = t; i4 < nv; i4 += 256) {
            int r = i4 / (DIN / 4), c = (i4 % (DIN / 4)) * 4;
            int gi = row0 + r;
            float4 v = make_float4(0.f, 0.f, 0.f, 0.f);
            if (gi < n) v = ld4(&Yin[(size_t)gi * DIN + c]);
            st4(&Ylds[r * DIN + c], v);
        }
    } else {
        for (int idx = t; idx < 64 * DIN; idx += 256) {
            int r = idx / DIN, c = idx - r * DIN;
            int gi = row0 + r;
            Ylds[idx] = (gi < n) ? Yin[(size_t)gi * DIN + c] : 0.f;
        }
    }

    const int c4 = (t & 31) * 4;
    const int rg = t >> 5;
    float4 acc[8];
#pragma unroll
    for (int r = 0; r < 8; ++r) acc[r] = make_float4(0.f, 0.f, 0.f, 0.f);

    for (int kc = 0; kc < DIN; kc += KC) {
        __syncthreads();
        for (int idx = t; idx < KC * 128; idx += 256)
            Wlds[idx] = WT[(size_t)(kc + (idx >> 7)) * 128 + (idx & 127)];
        __syncthreads();
#pragma unroll
        for (int kk = 0; kk < KC; ++kk) {
            float4 w4 = ld4(&Wlds[kk * 128 + c4]);
#pragma unroll
            for (int r = 0; r < 8; ++r) {
                float a = Ylds[(rg + 8 * r) * DIN + kc + kk];
                acc[r].x = fmaf(a, w4.x, acc[r].x);
                acc[r].y = fmaf(a, w4.y, acc[r].y);
                acc[r].z = fmaf(a, w4.z, acc[r].z);
                acc[r].w = fmaf(a, w4.w, acc[r].w);
            }
        }
    }

    float4 s4 = make_float4(0.f, 0.f, 0.f, 0.f), ss4 = make_float4(0.f, 0.f, 0.f, 0.f);
#pragma unroll
    for (int r = 0; r < 8; ++r) {
        int gi = row0 + rg + 8 * r;
        if (gi < n) st4(&Hout[(size_t)gi * 128 + c4], acc[r]);
        s4.x += acc[r].x; s4.y += acc[r].y; s4.z += acc[r].z; s4.w += acc[r].w;
        ss4.x += acc[r].x * acc[r].x; ss4.y += acc[r].y * acc[r].y;
        ss4.z += acc[r].z * acc[r].z; ss4.w += acc[r].w * acc[r].w;
    }
    __syncthreads();
    st4(&red[rg * 128 + c4], s4);
    __syncthreads();
    if (rg == 0) {
        float4 tot = make_float4(0.f, 0.f, 0.f, 0.f);
#pragma unroll
        for (int r = 0; r < 8; ++r) {
            float4 v = ld4(&red[r * 128 + c4]);
            tot.x += v.x; tot.y += v.y; tot.z += v.z; tot.w += v.w;
        }
        atomicAdd(&col_sum[c4 + 0], tot.x);
        atomicAdd(&col_sum[c4 + 1], tot.y);
        atomicAdd(&col_sum[c4 + 2], tot.z);
        atomicAdd(&col_sum[c4 + 3], tot.w);
    }
    __syncthreads();
    st4(&red[rg * 128 + c4], ss4);
    __syncthreads();
    if (rg == 0) {
        float4 tot = make_float4(0.f, 0.f, 0.f, 0.f);
#pragma unroll
        for (int r = 0; r < 8; ++r) {
            float4 v = ld4(&red[r * 128 + c4]);
            tot.x += v.x; tot.y += v.y; tot.z += v.z; tot.w += v.w;
        }
        atomicAdd(&col_sumsq[c4 + 0], tot.x);
        atomicAdd(&col_sumsq[c4 + 1], tot.y);
        atomicAdd(&col_sumsq[c4 + 2], tot.z);
        atomicAdd(&col_sumsq[c4 + 3], tot.w);
    }
}

// ---------------- BN finalize: scale/shift ----------------
__global__ void bn_finalize_k(const float* __restrict__ col_sum, const float* __restrict__ col_sumsq,
                              const float* __restrict__ g, const float* __restrict__ b,
                              float* __restrict__ scale, float* __restrict__ shift, int n) {
    int j = threadIdx.x;
    float inv_n = 1.0f / (float)n;
    float mean = col_sum[j] * inv_n;
    float var = col_sumsq[j] * inv_n - mean * mean;
    float a = g[j] * rsqrtf(var + BN_EPS);
    scale[j] = a;
    shift[j] = fmaf(-mean, a, b[j]);
}

// ---------------- GEMM2: relu(BN(h))@W2^T + b2, relu, store + graph pool ----------------
__global__ __launch_bounds__(256) void gemm2_pool_k(
    const float* __restrict__ Hpre, const float* __restrict__ scale, const float* __restrict__ shift,
    const float* __restrict__ WT /*[128][128]*/, const float* __restrict__ bias,
    const int* __restrict__ batch, float* __restrict__ Hout, float* __restrict__ pool, int n) {
    __shared__ __align__(16) float Ylds[64 * 128];
    __shared__ __align__(16) float Wlds[32 * 128];
    __shared__ __align__(16) float red[8 * 128];
    const int t = threadIdx.x;
    const int row0 = blockIdx.x * 64;

    for (int i4 = t; i4 < 2048; i4 += 256) {
        int r = i4 >> 5, c = (i4 & 31) * 4;
        int gi = row0 + r;
        float4 v = make_float4(0.f, 0.f, 0.f, 0.f);
        if (gi < n) {
            float4 h = ld4(&Hpre[(size_t)gi * 128 + c]);
            float4 a = ld4(&scale[c]);
            float4 b = ld4(&shift[c]);
            v.x = fmaxf(fmaf(h.x, a.x, b.x), 0.f);
            v.y = fmaxf(fmaf(h.y, a.y, b.y), 0.f);
            v.z = fmaxf(fmaf(h.z, a.z, b.z), 0.f);
            v.w = fmaxf(fmaf(h.w, a.w, b.w), 0.f);
        }
        st4(&Ylds[r * 128 + c], v);
    }

    const int c4 = (t & 31) * 4;
    const int rg = t >> 5;
    float4 acc[8];
#pragma unroll
    for (int r = 0; r < 8; ++r) acc[r] = make_float4(0.f, 0.f, 0.f, 0.f);

    for (int kc = 0; kc < 128; kc += 32) {
        __syncthreads();
        for (int idx = t; idx < 32 * 128; idx += 256)
            Wlds[idx] = WT[(size_t)(kc + (idx >> 7)) * 128 + (idx & 127)];
        __syncthreads();
#pragma unroll
        for (int kk = 0; kk < 32; ++kk) {
            float4 w4 = ld4(&Wlds[kk * 128 + c4]);
#pragma unroll
            for (int r = 0; r < 8; ++r) {
                float a = Ylds[(rg + 8 * r) * 128 + kc + kk];
                acc[r].x = fmaf(a, w4.x, acc[r].x);
                acc[r].y = fmaf(a, w4.y, acc[r].y);
                acc[r].z = fmaf(a, w4.z, acc[r].z);
                acc[r].w = fmaf(a, w4.w, acc[r].w);
            }
        }
    }

    float4 b4 = ld4(&bias[c4]);
    float4 outv[8];
#pragma unroll
    for (int r = 0; r < 8; ++r) {
        int gi = row0 + rg + 8 * r;
        float4 o;
        o.x = fmaxf(acc[r].x + b4.x, 0.f);
        o.y = fmaxf(acc[r].y + b4.y, 0.f);
        o.z = fmaxf(acc[r].z + b4.z, 0.f);
        o.w = fmaxf(acc[r].w + b4.w, 0.f);
        if (gi < n) st4(&Hout[(size_t)gi * 128 + c4], o);
        else o = make_float4(0.f, 0.f, 0.f, 0.f);
        outv[r] = o;
    }

    int lastRow = min(row0 + 63, n - 1);
    int gFirst = batch[row0];
    int gLast = batch[lastRow];
    if (gFirst == gLast) {
        // whole block in one graph: LDS reduce then 128 atomics
        float4 s = make_float4(0.f, 0.f, 0.f, 0.f);
#pragma unroll
        for (int r = 0; r < 8; ++r) { s.x += outv[r].x; s.y += outv[r].y; s.z += outv[r].z; s.w += outv[r].w; }
        __syncthreads();
        st4(&red[rg * 128 + c4], s);
        __syncthreads();
        if (rg == 0) {
            float4 tot = make_float4(0.f, 0.f, 0.f, 0.f);
#pragma unroll
            for (int r = 0; r < 8; ++r) {
                float4 v = ld4(&red[r * 128 + c4]);
                tot.x += v.x; tot.y += v.y; tot.z += v.z; tot.w += v.w;
            }
            float* p = &pool[(size_t)gFirst * OUT_STRIDE + c4];
            atomicAdd(&p[0], tot.x);
            atomicAdd(&p[1], tot.y);
            atomicAdd(&p[2], tot.z);
            atomicAdd(&p[3], tot.w);
        }
    } else {
#pragma unroll
        for (int r = 0; r < 8; ++r) {
            int gi = row0 + rg + 8 * r;
            if (gi < n) {
                int g = batch[gi];
                float* p = &pool[(size_t)g * OUT_STRIDE + c4];
                atomicAdd(&p[0], outv[r].x);
                atomicAdd(&p[1], outv[r].y);
                atomicAdd(&p[2], outv[r].z);
                atomicAdd(&p[3], outv[r].w);
            }
        }
    }
}

extern "C" void kernel_launch(void* const* d_in, const int* in_sizes, int n_in,
                              void* d_out, int out_size, void* d_ws, size_t ws_size,
                              hipStream_t stream) {
    const float* x = (const float*)d_in[0];
    const int* ei = (const int*)d_in[1];
    const float* ea = (const float*)d_in[2];
    const int* batch = (const int*)d_in[3];
    const int* srcArr = ei;
    const int* dstArr = ei + N_EDGES;

    const float *We[3], *be[3], *W1[3], *gP[3], *bP[3], *W2[3], *b2[3];
    for (int l = 0; l < 3; ++l) {
        int base = 4 + 7 * l;
        We[l] = (const float*)d_in[base + 0];
        be[l] = (const float*)d_in[base + 1];
        W1[l] = (const float*)d_in[base + 2];
        gP[l] = (const float*)d_in[base + 3];
        bP[l] = (const float*)d_in[base + 4];
        W2[l] = (const float*)d_in[base + 5];
        b2[l] = (const float*)d_in[base + 6];
    }

    char* w = (char*)d_ws;
    auto carve = [&](size_t bytes) {
        char* p = w;
        w += (bytes + 255) & ~(size_t)255;
        return p;
    };
    int* deg = (int*)carve((size_t)N_NODES * 4);
    int* rowstart = (int*)carve((size_t)(N_NODES + 1) * 4);
    int* cursor = (int*)carve((size_t)N_NODES * 4);
    int* adj_src = (int*)carve((size_t)N_EDGES * 4);
    float* adj_ea = (float*)carve((size_t)N_EDGES * 3 * 4);
    float* W1T0 = (float*)carve(9 * 128 * 4);
    float* W1T1 = (float*)carve(128 * 128 * 4);
    float* W1T2 = (float*)carve(128 * 128 * 4);
    float* W2T0 = (float*)carve(128 * 128 * 4);
    float* W2T1 = (float*)carve(128 * 128 * 4);
    float* W2T2 = (float*)carve(128 * 128 * 4);
    float* WeT1 = (float*)carve(3 * 128 * 4);
    float* WeT2 = (float*)carve(3 * 128 * 4);
    float* stats = (float*)carve(4 * 128 * 4);
    float* y0 = (float*)carve((size_t)N_NODES * 9 * 4);
    float* bufA = (float*)carve((size_t)N_NODES * 128 * 4);
    float* bufB = (float*)carve((size_t)N_NODES * 128 * 4);
    float* col_sum = stats;
    float* col_sumsq = stats + 128;
    float* scale = stats + 256;
    float* shift = stats + 384;

    hipMemsetAsync(deg, 0, (size_t)N_NODES * 4, stream);
    hipMemsetAsync(d_out, 0, (size_t)out_size * 4, stream);

    count_deg_k<<<(N_EDGES + 255) / 256, 256, 0, stream>>>(dstArr, deg, N_EDGES);
    scan_deg_k<<<1, 1024, 0, stream>>>(deg, rowstart, cursor, N_NODES);
    csr_fill_k<<<(N_EDGES + 255) / 256, 256, 0, stream>>>(srcArr, dstArr, ea, cursor, adj_src, adj_ea, N_EDGES);

    transpose_k<<<(128 * 9 + 255) / 256, 256, 0, stream>>>(W1[0], W1T0, 128, 9);
    transpose_k<<<64, 256, 0, stream>>>(W1[1], W1T1, 128, 128);
    transpose_k<<<64, 256, 0, stream>>>(W1[2], W1T2, 128, 128);
    transpose_k<<<64, 256, 0, stream>>>(W2[0], W2T0, 128, 128);
    transpose_k<<<64, 256, 0, stream>>>(W2[1], W2T1, 128, 128);
    transpose_k<<<64, 256, 0, stream>>>(W2[2], W2T2, 128, 128);
    transpose_k<<<2, 256, 0, stream>>>(We[1], WeT1, 128, 3);
    transpose_k<<<2, 256, 0, stream>>>(We[2], WeT2, 128, 3);

    const int gGemm = (N_NODES + 63) / 64;
    float* out_f = (float*)d_out;

    // ---- layer 0 (din=9) ----
    agg_d9_k<<<(N_NODES + 255) / 256, 256, 0, stream>>>(x, rowstart, adj_src, adj_ea, We[0], be[0], y0, N_NODES);
    hipMemsetAsync(stats, 0, 2 * 128 * 4, stream);
    gemm1_stats_k<9, 9><<<gGemm, 256, 0, stream>>>(y0, W1T0, bufA, col_sum, col_sumsq, N_NODES);
    bn_finalize_k<<<1, 128, 0, stream>>>(col_sum, col_sumsq, gP[0], bP[0], scale, shift, N_NODES);
    gemm2_pool_k<<<gGemm, 256, 0, stream>>>(bufA, scale, shift, W2T0, b2[0], batch, bufA, out_f + 0, N_NODES);

    // ---- layer 1 (din=128) ----
    agg_d128_k<<<(N_NODES + 7) / 8, 256, 0, stream>>>(bufA, rowstart, adj_src, adj_ea, WeT1, be[1], bufB, N_NODES);
    hipMemsetAsync(stats, 0, 2 * 128 * 4, stream);
    gemm1_stats_k<128, 32><<<gGemm, 256, 0, stream>>>(bufB, W1T1, bufB, col_sum, col_sumsq, N_NODES);
    bn_finalize_k<<<1, 128, 0, stream>>>(col_sum, col_sumsq, gP[1], bP[1], scale, shift, N_NODES);
    gemm2_pool_k<<<gGemm, 256, 0, stream>>>(bufB, scale, shift, W2T1, b2[1], batch, bufB, out_f + 128, N_NODES);

    // ---- layer 2 (din=128) ----
    agg_d128_k<<<(N_NODES + 7) / 8, 256, 0, stream>>>(bufB, rowstart, adj_src, adj_ea, WeT2, be[2], bufA, N_NODES);
    hipMemsetAsync(stats, 0, 2 * 128 * 4, stream);
    gemm1_stats_k<128, 32><<<gGemm, 256, 0, stream>>>(bufA, W1T2, bufA, col_sum, col_sumsq, N_NODES);
    bn_finalize_k<<<1, 128, 0, stream>>>(col_sum, col_sumsq, gP[2], bP[2], scale, shift, N_NODES);
    gemm2_pool_k<<<gGemm, 256, 0, stream>>>(bufA, scale, shift, W2T2, b2[2], batch, bufA, out_f + 256, N_NODES);
}

// Round 2
// 1124.207 us; speedup vs baseline: 1.0492x; 1.0492x over previous
//
#include <hip/hip_runtime.h>

#define N_NODES 50000
#define N_EDGES 800000
#define N_GRAPHS 500
#define DH 128
#define OUT_STRIDE 384
#define BN_EPS 1e-5f

__device__ __forceinline__ float4 ld4(const float* p) { return *(const float4*)p; }
__device__ __forceinline__ void st4(float* p, float4 v) { *(float4*)p = v; }

// ---------------- CSR build ----------------
__global__ void count_deg_k(const int* __restrict__ dst, int* __restrict__ deg, int E) {
    int e = blockIdx.x * 256 + threadIdx.x;
    if (e < E) atomicAdd(&deg[dst[e]], 1);
}

__global__ void scan_deg_k(const int* __restrict__ deg, int* __restrict__ rowstart,
                           int* __restrict__ cursor, int n) {
    __shared__ int part[1024];
    int t = threadIdx.x;
    int chunk = (n + 1023) >> 10;
    int i0 = t * chunk, i1 = min(i0 + chunk, n);
    int s = 0;
    for (int i = i0; i < i1; ++i) s += deg[i];
    part[t] = s;
    __syncthreads();
    for (int off = 1; off < 1024; off <<= 1) {
        int v = (t >= off) ? part[t - off] : 0;
        __syncthreads();
        part[t] += v;
        __syncthreads();
    }
    int base = part[t] - s;  // exclusive prefix
    for (int i = i0; i < i1; ++i) {
        int d = deg[i];
        rowstart[i] = base;
        cursor[i] = base;
        base += d;
    }
    if (t == 1023) rowstart[n] = part[1023];
}

__global__ void csr_fill_k(const int* __restrict__ src, const int* __restrict__ dst,
                           const float* __restrict__ ea, int* __restrict__ cursor,
                           int* __restrict__ adj_src, float* __restrict__ adj_ea, int E) {
    int e = blockIdx.x * 256 + threadIdx.x;
    if (e >= E) return;
    int pos = atomicAdd(&cursor[dst[e]], 1);
    adj_src[pos] = src[e];
    adj_ea[pos * 3 + 0] = ea[e * 3 + 0];
    adj_ea[pos * 3 + 1] = ea[e * 3 + 1];
    adj_ea[pos * 3 + 2] = ea[e * 3 + 2];
}

// ---------------- graph boundaries (batch is sorted) ----------------
__global__ void graph_bounds_k(const int* __restrict__ batch, int* __restrict__ gstart, int n, int G) {
    int i = blockIdx.x * 256 + threadIdx.x;
    if (i >= n) return;
    int b = batch[i];
    if (i == 0) {
        for (int g = 0; g <= b; ++g) gstart[g] = 0;
    } else {
        int p = batch[i - 1];
        for (int g = p + 1; g <= b; ++g) gstart[g] = i;
    }
    if (i == n - 1) {
        for (int g = b + 1; g <= G; ++g) gstart[g] = n;
    }
}

// ---------------- small transpose: in[R][C] -> out[C][R] ----------------
__global__ void transpose_k(const float* __restrict__ in, float* __restrict__ out, int R, int C) {
    int idx = blockIdx.x * 256 + threadIdx.x;
    if (idx < R * C) {
        int r = idx / C, c = idx - r * C;
        out[c * R + r] = in[idx];
    }
}

// ---------------- aggregation: y = x + sum_{e:dst=i} relu(x[src]+Lin(ea)) ----------------
__global__ __launch_bounds__(256) void agg_d9_k(
    const float* __restrict__ x, const int* __restrict__ rowstart,
    const int* __restrict__ adj_src, const float* __restrict__ adj_ea,
    const float* __restrict__ We /*[9][3]*/, const float* __restrict__ be,
    float* __restrict__ y, int n) {
    int i = blockIdx.x * 256 + threadIdx.x;
    if (i >= n) return;
    float w0[9], w1[9], w2[9], bb[9], acc[9];
#pragma unroll
    for (int j = 0; j < 9; ++j) {
        w0[j] = We[j * 3 + 0];
        w1[j] = We[j * 3 + 1];
        w2[j] = We[j * 3 + 2];
        bb[j] = be[j];
        acc[j] = x[(size_t)i * 9 + j];
    }
    int k1 = rowstart[i + 1];
    for (int k = rowstart[i]; k < k1; ++k) {
        int s = adj_src[k];
        float e0 = adj_ea[k * 3 + 0], e1 = adj_ea[k * 3 + 1], e2 = adj_ea[k * 3 + 2];
#pragma unroll
        for (int j = 0; j < 9; ++j) {
            float lin = fmaf(w0[j], e0, fmaf(w1[j], e1, fmaf(w2[j], e2, bb[j])));
            acc[j] += fmaxf(x[(size_t)s * 9 + j] + lin, 0.f);
        }
    }
#pragma unroll
    for (int j = 0; j < 9; ++j) y[(size_t)i * 9 + j] = acc[j];
}

__global__ __launch_bounds__(256) void agg_d128_k(
    const float* __restrict__ h, const int* __restrict__ rowstart,
    const int* __restrict__ adj_src, const float* __restrict__ adj_ea,
    const float* __restrict__ WeT /*[3][128]*/, const float* __restrict__ be,
    float* __restrict__ y, int n) {
    int lane = threadIdx.x & 31;
    int node = blockIdx.x * 8 + (threadIdx.x >> 5);
    if (node >= n) return;
    int c = lane * 4;
    float4 w0 = ld4(&WeT[0 * 128 + c]);
    float4 w1 = ld4(&WeT[1 * 128 + c]);
    float4 w2 = ld4(&WeT[2 * 128 + c]);
    float4 b4 = ld4(&be[c]);
    float4 acc = ld4(&h[(size_t)node * 128 + c]);
    int k = rowstart[node];
    int k1 = rowstart[node + 1];
    for (; k + 2 <= k1; k += 2) {
        int s0 = adj_src[k], s1 = adj_src[k + 1];
        float e00 = adj_ea[k * 3 + 0], e01 = adj_ea[k * 3 + 1], e02 = adj_ea[k * 3 + 2];
        float e10 = adj_ea[k * 3 + 3], e11 = adj_ea[k * 3 + 4], e12 = adj_ea[k * 3 + 5];
        float4 xa = ld4(&h[(size_t)s0 * 128 + c]);
        float4 xb = ld4(&h[(size_t)s1 * 128 + c]);
        float ax = fmaf(w0.x, e00, fmaf(w1.x, e01, fmaf(w2.x, e02, b4.x))) + xa.x;
        float ay = fmaf(w0.y, e00, fmaf(w1.y, e01, fmaf(w2.y, e02, b4.y))) + xa.y;
        float az = fmaf(w0.z, e00, fmaf(w1.z, e01, fmaf(w2.z, e02, b4.z))) + xa.z;
        float aw = fmaf(w0.w, e00, fmaf(w1.w, e01, fmaf(w2.w, e02, b4.w))) + xa.w;
        float bx = fmaf(w0.x, e10, fmaf(w1.x, e11, fmaf(w2.x, e12, b4.x))) + xb.x;
        float by = fmaf(w0.y, e10, fmaf(w1.y, e11, fmaf(w2.y, e12, b4.y))) + xb.y;
        float bz = fmaf(w0.z, e10, fmaf(w1.z, e11, fmaf(w2.z, e12, b4.z))) + xb.z;
        float bw = fmaf(w0.w, e10, fmaf(w1.w, e11, fmaf(w2.w, e12, b4.w))) + xb.w;
        acc.x += fmaxf(ax, 0.f) + fmaxf(bx, 0.f);
        acc.y += fmaxf(ay, 0.f) + fmaxf(by, 0.f);
        acc.z += fmaxf(az, 0.f) + fmaxf(bz, 0.f);
        acc.w += fmaxf(aw, 0.f) + fmaxf(bw, 0.f);
    }
    if (k < k1) {
        int s = adj_src[k];
        float e0 = adj_ea[k * 3 + 0], e1 = adj_ea[k * 3 + 1], e2 = adj_ea[k * 3 + 2];
        float4 xe = ld4(&h[(size_t)s * 128 + c]);
        float mx = fmaf(w0.x, e0, fmaf(w1.x, e1, fmaf(w2.x, e2, b4.x))) + xe.x;
        float my = fmaf(w0.y, e0, fmaf(w1.y, e1, fmaf(w2.y, e2, b4.y))) + xe.y;
        float mz = fmaf(w0.z, e0, fmaf(w1.z, e1, fmaf(w2.z, e2, b4.z))) + xe.z;
        float mw = fmaf(w0.w, e0, fmaf(w1.w, e1, fmaf(w2.w, e2, b4.w))) + xe.w;
        acc.x += fmaxf(mx, 0.f);
        acc.y += fmaxf(my, 0.f);
        acc.z += fmaxf(mz, 0.f);
        acc.w += fmaxf(mw, 0.f);
    }
    st4(&y[(size_t)node * 128 + c], acc);
}

// ---------------- GEMM1 (y @ W1^T) + BN column stats ----------------
// 32-row tile, 256 threads: rg = t>>5 (8 groups), thread rows rg+8j (j=0..3), cols (t&31)*4..+3
template <int DIN, int KC>
__global__ __launch_bounds__(256) void gemm1_stats_k(
    const float* __restrict__ Yin, const float* __restrict__ WT /*[DIN][128]*/,
    float* __restrict__ Hout, float* __restrict__ col_sum, float* __restrict__ col_sumsq, int n) {
    __shared__ __align__(16) float Ylds[32 * DIN];
    __shared__ __align__(16) float Wlds[KC * 128];
    __shared__ __align__(16) float red[8 * 128];
    const int t = threadIdx.x;
    const int row0 = blockIdx.x * 32;

    if constexpr (DIN % 4 == 0) {
        for (int i4 = t; i4 < 32 * DIN / 4; i4 += 256) {
            int r = i4 / (DIN / 4), c = (i4 % (DIN / 4)) * 4;
            int gi = row0 + r;
            float4 v = make_float4(0.f, 0.f, 0.f, 0.f);
            if (gi < n) v = ld4(&Yin[(size_t)gi * DIN + c]);
            st4(&Ylds[r * DIN + c], v);
        }
    } else {
        for (int idx = t; idx < 32 * DIN; idx += 256) {
            int r = idx / DIN, c = idx - r * DIN;
            int gi = row0 + r;
            Ylds[idx] = (gi < n) ? Yin[(size_t)gi * DIN + c] : 0.f;
        }
    }

    const int c4 = (t & 31) * 4;
    const int rg = t >> 5;
    float4 acc[4];
#pragma unroll
    for (int j = 0; j < 4; ++j) acc[j] = make_float4(0.f, 0.f, 0.f, 0.f);

    for (int kc = 0; kc < DIN; kc += KC) {
        __syncthreads();
        for (int i4 = t; i4 < KC * 32; i4 += 256) {
            int kr = i4 >> 5, cc = (i4 & 31) * 4;
            st4(&Wlds[kr * 128 + cc], ld4(&WT[(size_t)(kc + kr) * 128 + cc]));
        }
        __syncthreads();
#pragma unroll
        for (int kk = 0; kk < KC; ++kk) {
            float4 w4 = ld4(&Wlds[kk * 128 + c4]);
#pragma unroll
            for (int j = 0; j < 4; ++j) {
                float a = Ylds[(rg + 8 * j) * DIN + kc + kk];
                acc[j].x = fmaf(a, w4.x, acc[j].x);
                acc[j].y = fmaf(a, w4.y, acc[j].y);
                acc[j].z = fmaf(a, w4.z, acc[j].z);
                acc[j].w = fmaf(a, w4.w, acc[j].w);
            }
        }
    }

    float4 s4 = make_float4(0.f, 0.f, 0.f, 0.f), ss4 = make_float4(0.f, 0.f, 0.f, 0.f);
#pragma unroll
    for (int j = 0; j < 4; ++j) {
        int gi = row0 + rg + 8 * j;
        if (gi < n) st4(&Hout[(size_t)gi * 128 + c4], acc[j]);
        s4.x += acc[j].x; s4.y += acc[j].y; s4.z += acc[j].z; s4.w += acc[j].w;
        ss4.x += acc[j].x * acc[j].x; ss4.y += acc[j].y * acc[j].y;
        ss4.z += acc[j].z * acc[j].z; ss4.w += acc[j].w * acc[j].w;
    }
    __syncthreads();
    st4(&red[rg * 128 + c4], s4);
    __syncthreads();
    if (rg == 0) {
        float4 tot = make_float4(0.f, 0.f, 0.f, 0.f);
#pragma unroll
        for (int r = 0; r < 8; ++r) {
            float4 v = ld4(&red[r * 128 + c4]);
            tot.x += v.x; tot.y += v.y; tot.z += v.z; tot.w += v.w;
        }
        atomicAdd(&col_sum[c4 + 0], tot.x);
        atomicAdd(&col_sum[c4 + 1], tot.y);
        atomicAdd(&col_sum[c4 + 2], tot.z);
        atomicAdd(&col_sum[c4 + 3], tot.w);
    }
    __syncthreads();
    st4(&red[rg * 128 + c4], ss4);
    __syncthreads();
    if (rg == 0) {
        float4 tot = make_float4(0.f, 0.f, 0.f, 0.f);
#pragma unroll
        for (int r = 0; r < 8; ++r) {
            float4 v = ld4(&red[r * 128 + c4]);
            tot.x += v.x; tot.y += v.y; tot.z += v.z; tot.w += v.w;
        }
        atomicAdd(&col_sumsq[c4 + 0], tot.x);
        atomicAdd(&col_sumsq[c4 + 1], tot.y);
        atomicAdd(&col_sumsq[c4 + 2], tot.z);
        atomicAdd(&col_sumsq[c4 + 3], tot.w);
    }
}

// ---------------- BN finalize: scale/shift ----------------
__global__ void bn_finalize_k(const float* __restrict__ col_sum, const float* __restrict__ col_sumsq,
                              const float* __restrict__ g, const float* __restrict__ b,
                              float* __restrict__ scale, float* __restrict__ shift, int n) {
    int j = threadIdx.x;
    float inv_n = 1.0f / (float)n;
    float mean = col_sum[j] * inv_n;
    float var = col_sumsq[j] * inv_n - mean * mean;
    float a = g[j] * rsqrtf(var + BN_EPS);
    scale[j] = a;
    shift[j] = fmaf(-mean, a, b[j]);
}

// ---------------- GEMM2: relu(BN(h))@W2^T + b2, relu, store ----------------
__global__ __launch_bounds__(256) void gemm2_k(
    const float* __restrict__ Hpre, const float* __restrict__ scale, const float* __restrict__ shift,
    const float* __restrict__ WT /*[128][128]*/, const float* __restrict__ bias,
    float* __restrict__ Hout, int n) {
    __shared__ __align__(16) float Ylds[32 * 128];
    __shared__ __align__(16) float Wlds[32 * 128];
    const int t = threadIdx.x;
    const int row0 = blockIdx.x * 32;

    for (int i4 = t; i4 < 1024; i4 += 256) {
        int r = i4 >> 5, c = (i4 & 31) * 4;
        int gi = row0 + r;
        float4 v = make_float4(0.f, 0.f, 0.f, 0.f);
        if (gi < n) {
            float4 h = ld4(&Hpre[(size_t)gi * 128 + c]);
            float4 a = ld4(&scale[c]);
            float4 b = ld4(&shift[c]);
            v.x = fmaxf(fmaf(h.x, a.x, b.x), 0.f);
            v.y = fmaxf(fmaf(h.y, a.y, b.y), 0.f);
            v.z = fmaxf(fmaf(h.z, a.z, b.z), 0.f);
            v.w = fmaxf(fmaf(h.w, a.w, b.w), 0.f);
        }
        st4(&Ylds[r * 128 + c], v);
    }

    const int c4 = (t & 31) * 4;
    const int rg = t >> 5;
    float4 acc[4];
#pragma unroll
    for (int j = 0; j < 4; ++j) acc[j] = make_float4(0.f, 0.f, 0.f, 0.f);

    for (int kc = 0; kc < 128; kc += 32) {
        __syncthreads();
        for (int i4 = t; i4 < 1024; i4 += 256) {
            int kr = i4 >> 5, cc = (i4 & 31) * 4;
            st4(&Wlds[kr * 128 + cc], ld4(&WT[(size_t)(kc + kr) * 128 + cc]));
        }
        __syncthreads();
#pragma unroll
        for (int kk = 0; kk < 32; ++kk) {
            float4 w4 = ld4(&Wlds[kk * 128 + c4]);
#pragma unroll
            for (int j = 0; j < 4; ++j) {
                float a = Ylds[(rg + 8 * j) * 128 + kc + kk];
                acc[j].x = fmaf(a, w4.x, acc[j].x);
                acc[j].y = fmaf(a, w4.y, acc[j].y);
                acc[j].z = fmaf(a, w4.z, acc[j].z);
                acc[j].w = fmaf(a, w4.w, acc[j].w);
            }
        }
    }

    float4 b4 = ld4(&bias[c4]);
#pragma unroll
    for (int j = 0; j < 4; ++j) {
        int gi = row0 + rg + 8 * j;
        if (gi < n) {
            float4 o;
            o.x = fmaxf(acc[j].x + b4.x, 0.f);
            o.y = fmaxf(acc[j].y + b4.y, 0.f);
            o.z = fmaxf(acc[j].z + b4.z, 0.f);
            o.w = fmaxf(acc[j].w + b4.w, 0.f);
            st4(&Hout[(size_t)gi * 128 + c4], o);
        }
    }
}

// ---------------- per-graph pool (exclusive ranges, no atomics) ----------------
__global__ __launch_bounds__(256) void pool_k(
    const float* __restrict__ H, const int* __restrict__ gstart,
    float* __restrict__ out /* base + layer*128 */, int G) {
    int g = blockIdx.x;
    int t = threadIdx.x;
    int c = t & 127;
    int half = t >> 7;  // 0/1
    int r0 = gstart[g], r1 = gstart[g + 1];
    float s = 0.f;
    for (int r = r0 + half; r < r1; r += 2) s += H[(size_t)r * 128 + c];
    __shared__ float red[256];
    red[t] = s;
    __syncthreads();
    if (t < 128) out[(size_t)g * OUT_STRIDE + t] = red[t] + red[t + 128];
}

extern "C" void kernel_launch(void* const* d_in, const int* in_sizes, int n_in,
                              void* d_out, int out_size, void* d_ws, size_t ws_size,
                              hipStream_t stream) {
    const float* x = (const float*)d_in[0];
    const int* ei = (const int*)d_in[1];
    const float* ea = (const float*)d_in[2];
    const int* batch = (const int*)d_in[3];
    const int* srcArr = ei;
    const int* dstArr = ei + N_EDGES;

    const float *We[3], *be[3], *W1[3], *gP[3], *bP[3], *W2[3], *b2[3];
    for (int l = 0; l < 3; ++l) {
        int base = 4 + 7 * l;
        We[l] = (const float*)d_in[base + 0];
        be[l] = (const float*)d_in[base + 1];
        W1[l] = (const float*)d_in[base + 2];
        gP[l] = (const float*)d_in[base + 3];
        bP[l] = (const float*)d_in[base + 4];
        W2[l] = (const float*)d_in[base + 5];
        b2[l] = (const float*)d_in[base + 6];
    }

    char* w = (char*)d_ws;
    auto carve = [&](size_t bytes) {
        char* p = w;
        w += (bytes + 255) & ~(size_t)255;
        return p;
    };
    int* deg = (int*)carve((size_t)N_NODES * 4);
    int* rowstart = (int*)carve((size_t)(N_NODES + 1) * 4);
    int* cursor = (int*)carve((size_t)N_NODES * 4);
    int* gstart = (int*)carve((size_t)(N_GRAPHS + 1) * 4);
    int* adj_src = (int*)carve((size_t)N_EDGES * 4);
    float* adj_ea = (float*)carve((size_t)N_EDGES * 3 * 4);
    float* W1T0 = (float*)carve(9 * 128 * 4);
    float* W1T1 = (float*)carve(128 * 128 * 4);
    float* W1T2 = (float*)carve(128 * 128 * 4);
    float* W2T0 = (float*)carve(128 * 128 * 4);
    float* W2T1 = (float*)carve(128 * 128 * 4);
    float* W2T2 = (float*)carve(128 * 128 * 4);
    float* WeT1 = (float*)carve(3 * 128 * 4);
    float* WeT2 = (float*)carve(3 * 128 * 4);
    float* stats = (float*)carve(4 * 128 * 4);
    float* y0 = (float*)carve((size_t)N_NODES * 9 * 4);
    float* bufA = (float*)carve((size_t)N_NODES * 128 * 4);
    float* bufB = (float*)carve((size_t)N_NODES * 128 * 4);
    float* col_sum = stats;
    float* col_sumsq = stats + 128;
    float* scale = stats + 256;
    float* shift = stats + 384;

    hipMemsetAsync(deg, 0, (size_t)N_NODES * 4, stream);

    count_deg_k<<<(N_EDGES + 255) / 256, 256, 0, stream>>>(dstArr, deg, N_EDGES);
    scan_deg_k<<<1, 1024, 0, stream>>>(deg, rowstart, cursor, N_NODES);
    csr_fill_k<<<(N_EDGES + 255) / 256, 256, 0, stream>>>(srcArr, dstArr, ea, cursor, adj_src, adj_ea, N_EDGES);
    graph_bounds_k<<<(N_NODES + 255) / 256, 256, 0, stream>>>(batch, gstart, N_NODES, N_GRAPHS);

    transpose_k<<<(128 * 9 + 255) / 256, 256, 0, stream>>>(W1[0], W1T0, 128, 9);
    transpose_k<<<64, 256, 0, stream>>>(W1[1], W1T1, 128, 128);
    transpose_k<<<64, 256, 0, stream>>>(W1[2], W1T2, 128, 128);
    transpose_k<<<64, 256, 0, stream>>>(W2[0], W2T0, 128, 128);
    transpose_k<<<64, 256, 0, stream>>>(W2[1], W2T1, 128, 128);
    transpose_k<<<64, 256, 0, stream>>>(W2[2], W2T2, 128, 128);
    transpose_k<<<2, 256, 0, stream>>>(We[1], WeT1, 128, 3);
    transpose_k<<<2, 256, 0, stream>>>(We[2], WeT2, 128, 3);

    const int gGemm = (N_NODES + 31) / 32;
    float* out_f = (float*)d_out;

    // ---- layer 0 (din=9) ----
    agg_d9_k<<<(N_NODES + 255) / 256, 256, 0, stream>>>(x, rowstart, adj_src, adj_ea, We[0], be[0], y0, N_NODES);
    hipMemsetAsync(stats, 0, 2 * 128 * 4, stream);
    gemm1_stats_k<9, 9><<<gGemm, 256, 0, stream>>>(y0, W1T0, bufA, col_sum, col_sumsq, N_NODES);
    bn_finalize_k<<<1, 128, 0, stream>>>(col_sum, col_sumsq, gP[0], bP[0], scale, shift, N_NODES);
    gemm2_k<<<gGemm, 256, 0, stream>>>(bufA, scale, shift, W2T0, b2[0], bufA, N_NODES);
    pool_k<<<N_GRAPHS, 256, 0, stream>>>(bufA, gstart, out_f + 0, N_GRAPHS);

    // ---- layer 1 (din=128) ----
    agg_d128_k<<<(N_NODES + 7) / 8, 256, 0, stream>>>(bufA, rowstart, adj_src, adj_ea, WeT1, be[1], bufB, N_NODES);
    hipMemsetAsync(stats, 0, 2 * 128 * 4, stream);
    gemm1_stats_k<128, 32><<<gGemm, 256, 0, stream>>>(bufB, W1T1, bufB, col_sum, col_sumsq, N_NODES);
    bn_finalize_k<<<1, 128, 0, stream>>>(col_sum, col_sumsq, gP[1], bP[1], scale, shift, N_NODES);
    gemm2_k<<<gGemm, 256, 0, stream>>>(bufB, scale, shift, W2T1, b2[1], bufB, N_NODES);
    pool_k<<<N_GRAPHS, 256, 0, stream>>>(bufB, gstart, out_f + 128, N_GRAPHS);

    // ---- layer 2 (din=128) ----
    agg_d128_k<<<(N_NODES + 7) / 8, 256, 0, stream>>>(bufB, rowstart, adj_src, adj_ea, WeT2, be[2], bufA, N_NODES);
    hipMemsetAsync(stats, 0, 2 * 128 * 4, stream);
    gemm1_stats_k<128, 32><<<gGemm, 256, 0, stream>>>(bufA, W1T2, bufA, col_sum, col_sumsq, N_NODES);
    bn_finalize_k<<<1, 128, 0, stream>>>(col_sum, col_sumsq, gP[2], bP[2], scale, shift, N_NODES);
    gemm2_k<<<gGemm, 256, 0, stream>>>(bufA, scale, shift, W2T2, b2[2], bufA, N_NODES);
    pool_k<<<N_GRAPHS, 256, 0, stream>>>(bufA, gstart, out_f + 256, N_NODES);
}

// Round 3
// 644.042 us; speedup vs baseline: 1.8314x; 1.7455x over previous
//
#include <hip/hip_runtime.h>

#define N_NODES 50000
#define N_EDGES 800000
#define N_GRAPHS 500
#define DH 128
#define OUT_STRIDE 384
#define BN_EPS 1e-5f

typedef __attribute__((ext_vector_type(8))) short bf16x8;
typedef __attribute__((ext_vector_type(4))) float f32x4;

__device__ __forceinline__ float4 ld4(const float* p) { return *(const float4*)p; }
__device__ __forceinline__ void st4(float* p, float4 v) { *(float4*)p = v; }

__device__ __forceinline__ short f2bf(float f) {
    union { float f; unsigned u; } v; v.f = f;
    unsigned r = v.u + 0x7FFFu + ((v.u >> 16) & 1u);
    return (short)(r >> 16);
}

// ---------------- CSR build ----------------
__global__ void count_deg_k(const int* __restrict__ dst, int* __restrict__ deg, int E) {
    int e = blockIdx.x * 256 + threadIdx.x;
    if (e < E) atomicAdd(&deg[dst[e]], 1);
}

__global__ void scan_deg_k(const int* __restrict__ deg, int* __restrict__ rowstart,
                           int* __restrict__ cursor, int n) {
    __shared__ int part[1024];
    int t = threadIdx.x;
    int chunk = (n + 1023) >> 10;
    int i0 = t * chunk, i1 = min(i0 + chunk, n);
    int s = 0;
    for (int i = i0; i < i1; ++i) s += deg[i];
    part[t] = s;
    __syncthreads();
    for (int off = 1; off < 1024; off <<= 1) {
        int v = (t >= off) ? part[t - off] : 0;
        __syncthreads();
        part[t] += v;
        __syncthreads();
    }
    int base = part[t] - s;  // exclusive prefix
    for (int i = i0; i < i1; ++i) {
        int d = deg[i];
        rowstart[i] = base;
        cursor[i] = base;
        base += d;
    }
    if (t == 1023) rowstart[n] = part[1023];
}

__global__ void csr_fill_k(const int* __restrict__ src, const int* __restrict__ dst,
                           const float* __restrict__ ea, int* __restrict__ cursor,
                           int* __restrict__ adj_src, float* __restrict__ adj_ea, int E) {
    int e = blockIdx.x * 256 + threadIdx.x;
    if (e >= E) return;
    int pos = atomicAdd(&cursor[dst[e]], 1);
    adj_src[pos] = src[e];
    adj_ea[pos * 3 + 0] = ea[e * 3 + 0];
    adj_ea[pos * 3 + 1] = ea[e * 3 + 1];
    adj_ea[pos * 3 + 2] = ea[e * 3 + 2];
}

// ---------------- graph boundaries (batch is sorted) ----------------
__global__ void graph_bounds_k(const int* __restrict__ batch, int* __restrict__ gstart, int n, int G) {
    int i = blockIdx.x * 256 + threadIdx.x;
    if (i >= n) return;
    int b = batch[i];
    if (i == 0) {
        for (int g = 0; g <= b; ++g) gstart[g] = 0;
    } else {
        int p = batch[i - 1];
        for (int g = p + 1; g <= b; ++g) gstart[g] = i;
    }
    if (i == n - 1) {
        for (int g = b + 1; g <= G; ++g) gstart[g] = n;
    }
}

// ---------------- small transpose: in[R][C] -> out[C][R] ----------------
__global__ void transpose_k(const float* __restrict__ in, float* __restrict__ out, int R, int C) {
    int idx = blockIdx.x * 256 + threadIdx.x;
    if (idx < R * C) {
        int r = idx / C, c = idx - r * C;
        out[c * R + r] = in[idx];
    }
}

// ---------------- W -> bf16 MFMA B-fragment order ----------------
// Wt[k][n] = W[n][k] (W is [128][din] row-major). Chunk layout: 8 bf16 along k.
// chunkIdx = (nt*NC + c)*16 + n16, with n = nt*16+n16, k = c*8+j, NC = KP/8.
__global__ void wfrag_k(const float* __restrict__ W, short* __restrict__ WF, int din, int KP) {
    int NC = KP >> 3;
    int total = 8 * NC * 16;
    int idx = blockIdx.x * 256 + threadIdx.x;
    if (idx >= total) return;
    int n16 = idx & 15;
    int rest = idx >> 4;
    int c = rest % NC;
    int nt = rest / NC;
    int n = nt * 16 + n16;
    union { short s[8]; int4 v; } u;
#pragma unroll
    for (int j = 0; j < 8; ++j) {
        int k = c * 8 + j;
        float val = (k < din) ? W[(size_t)n * din + k] : 0.f;
        u.s[j] = f2bf(val);
    }
    ((int4*)WF)[idx] = u.v;
}

// ---------------- aggregation: y = x + sum_{e:dst=i} relu(x[src]+Lin(ea)) ----------------
// Layer 0: writes y padded to stride 32 (zeros beyond col 9) for the K=32 MFMA.
__global__ __launch_bounds__(256) void agg_d9_k(
    const float* __restrict__ x, const int* __restrict__ rowstart,
    const int* __restrict__ adj_src, const float* __restrict__ adj_ea,
    const float* __restrict__ We /*[9][3]*/, const float* __restrict__ be,
    float* __restrict__ y /*[n][32]*/, int n) {
    int i = blockIdx.x * 256 + threadIdx.x;
    if (i >= n) return;
    float w0[9], w1[9], w2[9], bb[9], acc[9];
#pragma unroll
    for (int j = 0; j < 9; ++j) {
        w0[j] = We[j * 3 + 0];
        w1[j] = We[j * 3 + 1];
        w2[j] = We[j * 3 + 2];
        bb[j] = be[j];
        acc[j] = x[(size_t)i * 9 + j];
    }
    int k1 = rowstart[i + 1];
    for (int k = rowstart[i]; k < k1; ++k) {
        int s = adj_src[k];
        float e0 = adj_ea[k * 3 + 0], e1 = adj_ea[k * 3 + 1], e2 = adj_ea[k * 3 + 2];
#pragma unroll
        for (int j = 0; j < 9; ++j) {
            float lin = fmaf(w0[j], e0, fmaf(w1[j], e1, fmaf(w2[j], e2, bb[j])));
            acc[j] += fmaxf(x[(size_t)s * 9 + j] + lin, 0.f);
        }
    }
    float* yp = y + (size_t)i * 32;
#pragma unroll
    for (int j = 0; j < 9; ++j) yp[j] = acc[j];
#pragma unroll
    for (int j = 9; j < 32; ++j) yp[j] = 0.f;
}

__global__ __launch_bounds__(256) void agg_d128_k(
    const float* __restrict__ h, const int* __restrict__ rowstart,
    const int* __restrict__ adj_src, const float* __restrict__ adj_ea,
    const float* __restrict__ WeT /*[3][128]*/, const float* __restrict__ be,
    float* __restrict__ y, int n) {
    int lane = threadIdx.x & 31;
    int node = blockIdx.x * 8 + (threadIdx.x >> 5);
    if (node >= n) return;
    int c = lane * 4;
    float4 w0 = ld4(&WeT[0 * 128 + c]);
    float4 w1 = ld4(&WeT[1 * 128 + c]);
    float4 w2 = ld4(&WeT[2 * 128 + c]);
    float4 b4 = ld4(&be[c]);
    float4 acc = ld4(&h[(size_t)node * 128 + c]);
    int k = rowstart[node];
    int k1 = rowstart[node + 1];
    for (; k + 2 <= k1; k += 2) {
        int s0 = adj_src[k], s1 = adj_src[k + 1];
        float e00 = adj_ea[k * 3 + 0], e01 = adj_ea[k * 3 + 1], e02 = adj_ea[k * 3 + 2];
        float e10 = adj_ea[k * 3 + 3], e11 = adj_ea[k * 3 + 4], e12 = adj_ea[k * 3 + 5];
        float4 xa = ld4(&h[(size_t)s0 * 128 + c]);
        float4 xb = ld4(&h[(size_t)s1 * 128 + c]);
        float ax = fmaf(w0.x, e00, fmaf(w1.x, e01, fmaf(w2.x, e02, b4.x))) + xa.x;
        float ay = fmaf(w0.y, e00, fmaf(w1.y, e01, fmaf(w2.y, e02, b4.y))) + xa.y;
        float az = fmaf(w0.z, e00, fmaf(w1.z, e01, fmaf(w2.z, e02, b4.z))) + xa.z;
        float aw = fmaf(w0.w, e00, fmaf(w1.w, e01, fmaf(w2.w, e02, b4.w))) + xa.w;
        float bx = fmaf(w0.x, e10, fmaf(w1.x, e11, fmaf(w2.x, e12, b4.x))) + xb.x;
        float by = fmaf(w0.y, e10, fmaf(w1.y, e11, fmaf(w2.y, e12, b4.y))) + xb.y;
        float bz = fmaf(w0.z, e10, fmaf(w1.z, e11, fmaf(w2.z, e12, b4.z))) + xb.z;
        float bw = fmaf(w0.w, e10, fmaf(w1.w, e11, fmaf(w2.w, e12, b4.w))) + xb.w;
        acc.x += fmaxf(ax, 0.f) + fmaxf(bx, 0.f);
        acc.y += fmaxf(ay, 0.f) + fmaxf(by, 0.f);
        acc.z += fmaxf(az, 0.f) + fmaxf(bz, 0.f);
        acc.w += fmaxf(aw, 0.f) + fmaxf(bw, 0.f);
    }
    if (k < k1) {
        int s = adj_src[k];
        float e0 = adj_ea[k * 3 + 0], e1 = adj_ea[k * 3 + 1], e2 = adj_ea[k * 3 + 2];
        float4 xe = ld4(&h[(size_t)s * 128 + c]);
        float mx = fmaf(w0.x, e0, fmaf(w1.x, e1, fmaf(w2.x, e2, b4.x))) + xe.x;
        float my = fmaf(w0.y, e0, fmaf(w1.y, e1, fmaf(w2.y, e2, b4.y))) + xe.y;
        float mz = fmaf(w0.z, e0, fmaf(w1.z, e1, fmaf(w2.z, e2, b4.z))) + xe.z;
        float mw = fmaf(w0.w, e0, fmaf(w1.w, e1, fmaf(w2.w, e2, b4.w))) + xe.w;
        acc.x += fmaxf(mx, 0.f);
        acc.y += fmaxf(my, 0.f);
        acc.z += fmaxf(mz, 0.f);
        acc.w += fmaxf(mw, 0.f);
    }
    st4(&y[(size_t)node * 128 + c], acc);
}

// ---------------- A-fragment helpers ----------------
__device__ __forceinline__ bf16x8 loadA(const float* p, bool v) {
    union { short s[8]; bf16x8 v8; } u;
    if (v) {
        float4 a = ld4(p), b = ld4(p + 4);
        u.s[0] = f2bf(a.x); u.s[1] = f2bf(a.y); u.s[2] = f2bf(a.z); u.s[3] = f2bf(a.w);
        u.s[4] = f2bf(b.x); u.s[5] = f2bf(b.y); u.s[6] = f2bf(b.z); u.s[7] = f2bf(b.w);
    } else {
#pragma unroll
        for (int j = 0; j < 8; ++j) u.s[j] = 0;
    }
    return u.v8;
}

__device__ __forceinline__ bf16x8 loadA_bn(const float* p, bool v,
                                           float4 sc0, float4 sc1, float4 sh0, float4 sh1) {
    union { short s[8]; bf16x8 v8; } u;
    if (v) {
        float4 a = ld4(p), b = ld4(p + 4);
        u.s[0] = f2bf(fmaxf(fmaf(a.x, sc0.x, sh0.x), 0.f));
        u.s[1] = f2bf(fmaxf(fmaf(a.y, sc0.y, sh0.y), 0.f));
        u.s[2] = f2bf(fmaxf(fmaf(a.z, sc0.z, sh0.z), 0.f));
        u.s[3] = f2bf(fmaxf(fmaf(a.w, sc0.w, sh0.w), 0.f));
        u.s[4] = f2bf(fmaxf(fmaf(b.x, sc1.x, sh1.x), 0.f));
        u.s[5] = f2bf(fmaxf(fmaf(b.y, sc1.y, sh1.y), 0.f));
        u.s[6] = f2bf(fmaxf(fmaf(b.z, sc1.z, sh1.z), 0.f));
        u.s[7] = f2bf(fmaxf(fmaf(b.w, sc1.w, sh1.w), 0.f));
    } else {
#pragma unroll
        for (int j = 0; j < 8; ++j) u.s[j] = 0;
    }
    return u.v8;
}

// ---------------- MFMA GEMM1: H = Y @ Wt, + BN column stats ----------------
// Block: 256 thr = 4 waves; wave w handles rows [blk*128 + w*32, +32), all 128 cols.
// A-frags straight from global fp32 (converted); B-frags from LDS (pre-swizzled WF).
// In-place safe: each wave reads only its own 32 rows, stores after all reads.
template <int KP>
__global__ __launch_bounds__(256) void mgemm1_k(
    const float* Y /* [n][KP] */, const short* __restrict__ WF,
    float* Hout /* [n][128] */, float* __restrict__ col_sum, float* __restrict__ col_sumsq, int n) {
    constexpr int NC = KP / 8;
    constexpr int KB = KP / 32;
    __shared__ short Wlds[8 * NC * 16 * 8];
    __shared__ float red[256];
    const int t = threadIdx.x;
    const int lane = t & 63, w = t >> 6;
    const int l15 = lane & 15, q = lane >> 4;
    const int row0 = blockIdx.x * 128 + w * 32;

    {
        const int4* s = (const int4*)WF;
        int4* d = (int4*)Wlds;
        for (int i = t; i < 8 * NC * 16; i += 256) d[i] = s[i];
    }
    red[t] = 0.f;
    __syncthreads();

    f32x4 acc[2][8];
#pragma unroll
    for (int rt = 0; rt < 2; ++rt)
#pragma unroll
        for (int nt = 0; nt < 8; ++nt) acc[rt][nt] = (f32x4){0.f, 0.f, 0.f, 0.f};

    const int r0 = row0 + l15, r1 = row0 + 16 + l15;
    const float* p0 = Y + (size_t)r0 * KP + q * 8;
    const float* p1 = Y + (size_t)r1 * KP + q * 8;
    const bool v0 = r0 < n, v1 = r1 < n;
    const bf16x8* WL = (const bf16x8*)Wlds;

#pragma unroll
    for (int b = 0; b < KB; ++b) {
        bf16x8 a0 = loadA(p0 + b * 32, v0);
        bf16x8 a1 = loadA(p1 + b * 32, v1);
#pragma unroll
        for (int nt = 0; nt < 8; ++nt) {
            bf16x8 bf = WL[(nt * NC + b * 4 + q) * 16 + l15];
            acc[0][nt] = __builtin_amdgcn_mfma_f32_16x16x32_bf16(a0, bf, acc[0][nt], 0, 0, 0);
            acc[1][nt] = __builtin_amdgcn_mfma_f32_16x16x32_bf16(a1, bf, acc[1][nt], 0, 0, 0);
        }
    }

#pragma unroll
    for (int nt = 0; nt < 8; ++nt) {
        float s = 0.f, ss = 0.f;
#pragma unroll
        for (int rt = 0; rt < 2; ++rt) {
            int rb = row0 + rt * 16 + q * 4;
#pragma unroll
            for (int i = 0; i < 4; ++i) {
                float d = acc[rt][nt][i];
                int r = rb + i;
                if (r < n) Hout[(size_t)r * 128 + nt * 16 + l15] = d;
                s += d;
                ss += d * d;
            }
        }
        s += __shfl_xor(s, 16);
        s += __shfl_xor(s, 32);
        ss += __shfl_xor(ss, 16);
        ss += __shfl_xor(ss, 32);
        if (lane < 16) {
            atomicAdd(&red[nt * 16 + l15], s);
            atomicAdd(&red[128 + nt * 16 + l15], ss);
        }
    }
    __syncthreads();
    if (t < 128) atomicAdd(&col_sum[t], red[t]);
    else atomicAdd(&col_sumsq[t - 128], red[t]);
}

// ---------------- BN finalize: scale/shift ----------------
__global__ void bn_finalize_k(const float* __restrict__ col_sum, const float* __restrict__ col_sumsq,
                              const float* __restrict__ g, const float* __restrict__ b,
                              float* __restrict__ scale, float* __restrict__ shift, int n) {
    int j = threadIdx.x;
    float inv_n = 1.0f / (float)n;
    float mean = col_sum[j] * inv_n;
    float var = col_sumsq[j] * inv_n - mean * mean;
    float a = g[j] * rsqrtf(var + BN_EPS);
    scale[j] = a;
    shift[j] = fmaf(-mean, a, b[j]);
}

// ---------------- MFMA GEMM2: h = relu( relu(BN(Hpre)) @ Wt + b2 ) ----------------
__global__ __launch_bounds__(256) void mgemm2_k(
    const float* Hpre, const short* __restrict__ WF,
    const float* __restrict__ scale, const float* __restrict__ shift,
    const float* __restrict__ bias, float* Hout, int n) {
    constexpr int NC = 16;
    __shared__ short Wlds[8 * NC * 16 * 8];
    const int t = threadIdx.x;
    const int lane = t & 63, w = t >> 6;
    const int l15 = lane & 15, q = lane >> 4;
    const int row0 = blockIdx.x * 128 + w * 32;

    {
        const int4* s = (const int4*)WF;
        int4* d = (int4*)Wlds;
        for (int i = t; i < 8 * NC * 16; i += 256) d[i] = s[i];
    }
    __syncthreads();

    f32x4 acc[2][8];
#pragma unroll
    for (int rt = 0; rt < 2; ++rt)
#pragma unroll
        for (int nt = 0; nt < 8; ++nt) acc[rt][nt] = (f32x4){0.f, 0.f, 0.f, 0.f};

    const int r0 = row0 + l15, r1 = row0 + 16 + l15;
    const float* p0 = Hpre + (size_t)r0 * 128 + q * 8;
    const float* p1 = Hpre + (size_t)r1 * 128 + q * 8;
    const bool v0 = r0 < n, v1 = r1 < n;
    const bf16x8* WL = (const bf16x8*)Wlds;

#pragma unroll
    for (int b = 0; b < 4; ++b) {
        const int k0 = b * 32 + q * 8;
        float4 sc0 = ld4(&scale[k0]), sc1 = ld4(&scale[k0 + 4]);
        float4 sh0 = ld4(&shift[k0]), sh1 = ld4(&shift[k0 + 4]);
        bf16x8 a0 = loadA_bn(p0 + b * 32, v0, sc0, sc1, sh0, sh1);
        bf16x8 a1 = loadA_bn(p1 + b * 32, v1, sc0, sc1, sh0, sh1);
#pragma unroll
        for (int nt = 0; nt < 8; ++nt) {
            bf16x8 bf = WL[(nt * NC + b * 4 + q) * 16 + l15];
            acc[0][nt] = __builtin_amdgcn_mfma_f32_16x16x32_bf16(a0, bf, acc[0][nt], 0, 0, 0);
            acc[1][nt] = __builtin_amdgcn_mfma_f32_16x16x32_bf16(a1, bf, acc[1][nt], 0, 0, 0);
        }
    }

#pragma unroll
    for (int nt = 0; nt < 8; ++nt) {
        float bcol = bias[nt * 16 + l15];
#pragma unroll
        for (int rt = 0; rt < 2; ++rt) {
            int rb = row0 + rt * 16 + q * 4;
#pragma unroll
            for (int i = 0; i < 4; ++i) {
                int r = rb + i;
                if (r < n) Hout[(size_t)r * 128 + nt * 16 + l15] = fmaxf(acc[rt][nt][i] + bcol, 0.f);
            }
        }
    }
}

// ---------------- per-graph pool (exclusive ranges, no atomics) ----------------
__global__ __launch_bounds__(256) void pool_k(
    const float* __restrict__ H, const int* __restrict__ gstart,
    float* __restrict__ out /* base + layer*128 */) {
    int g = blockIdx.x;
    int t = threadIdx.x;
    int c = t & 127;
    int half = t >> 7;  // 0/1
    int r0 = gstart[g], r1 = gstart[g + 1];
    float s = 0.f;
    for (int r = r0 + half; r < r1; r += 2) s += H[(size_t)r * 128 + c];
    __shared__ float red[256];
    red[t] = s;
    __syncthreads();
    if (t < 128) out[(size_t)g * OUT_STRIDE + t] = red[t] + red[t + 128];
}

extern "C" void kernel_launch(void* const* d_in, const int* in_sizes, int n_in,
                              void* d_out, int out_size, void* d_ws, size_t ws_size,
                              hipStream_t stream) {
    const float* x = (const float*)d_in[0];
    const int* ei = (const int*)d_in[1];
    const float* ea = (const float*)d_in[2];
    const int* batch = (const int*)d_in[3];
    const int* srcArr = ei;
    const int* dstArr = ei + N_EDGES;

    const float *We[3], *be[3], *W1[3], *gP[3], *bP[3], *W2[3], *b2[3];
    for (int l = 0; l < 3; ++l) {
        int base = 4 + 7 * l;
        We[l] = (const float*)d_in[base + 0];
        be[l] = (const float*)d_in[base + 1];
        W1[l] = (const float*)d_in[base + 2];
        gP[l] = (const float*)d_in[base + 3];
        bP[l] = (const float*)d_in[base + 4];
        W2[l] = (const float*)d_in[base + 5];
        b2[l] = (const float*)d_in[base + 6];
    }

    char* w = (char*)d_ws;
    auto carve = [&](size_t bytes) {
        char* p = w;
        w += (bytes + 255) & ~(size_t)255;
        return p;
    };
    int* deg = (int*)carve((size_t)N_NODES * 4);
    int* rowstart = (int*)carve((size_t)(N_NODES + 1) * 4);
    int* cursor = (int*)carve((size_t)N_NODES * 4);
    int* gstart = (int*)carve((size_t)(N_GRAPHS + 1) * 4);
    int* adj_src = (int*)carve((size_t)N_EDGES * 4);
    float* adj_ea = (float*)carve((size_t)N_EDGES * 3 * 4);
    float* WeT1 = (float*)carve(3 * 128 * 4);
    float* WeT2 = (float*)carve(3 * 128 * 4);
    short* WF1_0 = (short*)carve(8 * 4 * 16 * 8 * 2);    // KP=32
    short* WF1_1 = (short*)carve(8 * 16 * 16 * 8 * 2);   // KP=128
    short* WF1_2 = (short*)carve(8 * 16 * 16 * 8 * 2);
    short* WF2_0 = (short*)carve(8 * 16 * 16 * 8 * 2);
    short* WF2_1 = (short*)carve(8 * 16 * 16 * 8 * 2);
    short* WF2_2 = (short*)carve(8 * 16 * 16 * 8 * 2);
    float* stats = (float*)carve(4 * 128 * 4);
    float* y0p = (float*)carve((size_t)N_NODES * 32 * 4);
    float* hA = (float*)carve((size_t)N_NODES * 128 * 4);
    float* ybuf = (float*)carve((size_t)N_NODES * 128 * 4);
    float* col_sum = stats;
    float* col_sumsq = stats + 128;
    float* scale = stats + 256;
    float* shift = stats + 384;

    hipMemsetAsync(deg, 0, (size_t)N_NODES * 4, stream);

    count_deg_k<<<(N_EDGES + 255) / 256, 256, 0, stream>>>(dstArr, deg, N_EDGES);
    scan_deg_k<<<1, 1024, 0, stream>>>(deg, rowstart, cursor, N_NODES);
    csr_fill_k<<<(N_EDGES + 255) / 256, 256, 0, stream>>>(srcArr, dstArr, ea, cursor, adj_src, adj_ea, N_EDGES);
    graph_bounds_k<<<(N_NODES + 255) / 256, 256, 0, stream>>>(batch, gstart, N_NODES, N_GRAPHS);

    transpose_k<<<2, 256, 0, stream>>>(We[1], WeT1, 128, 3);
    transpose_k<<<2, 256, 0, stream>>>(We[2], WeT2, 128, 3);

    wfrag_k<<<2, 256, 0, stream>>>(W1[0], WF1_0, 9, 32);
    wfrag_k<<<8, 256, 0, stream>>>(W1[1], WF1_1, 128, 128);
    wfrag_k<<<8, 256, 0, stream>>>(W1[2], WF1_2, 128, 128);
    wfrag_k<<<8, 256, 0, stream>>>(W2[0], WF2_0, 128, 128);
    wfrag_k<<<8, 256, 0, stream>>>(W2[1], WF2_1, 128, 128);
    wfrag_k<<<8, 256, 0, stream>>>(W2[2], WF2_2, 128, 128);

    const int gM = (N_NODES + 127) / 128;
    float* out_f = (float*)d_out;

    // ---- layer 0 (K=32 padded from din=9) ----
    agg_d9_k<<<(N_NODES + 255) / 256, 256, 0, stream>>>(x, rowstart, adj_src, adj_ea, We[0], be[0], y0p, N_NODES);
    hipMemsetAsync(stats, 0, 2 * 128 * 4, stream);
    mgemm1_k<32><<<gM, 256, 0, stream>>>(y0p, WF1_0, hA, col_sum, col_sumsq, N_NODES);
    bn_finalize_k<<<1, 128, 0, stream>>>(col_sum, col_sumsq, gP[0], bP[0], scale, shift, N_NODES);
    mgemm2_k<<<gM, 256, 0, stream>>>(hA, WF2_0, scale, shift, b2[0], hA, N_NODES);
    pool_k<<<N_GRAPHS, 256, 0, stream>>>(hA, gstart, out_f + 0);

    // ---- layer 1 ----
    agg_d128_k<<<(N_NODES + 7) / 8, 256, 0, stream>>>(hA, rowstart, adj_src, adj_ea, WeT1, be[1], ybuf, N_NODES);
    hipMemsetAsync(stats, 0, 2 * 128 * 4, stream);
    mgemm1_k<128><<<gM, 256, 0, stream>>>(ybuf, WF1_1, ybuf, col_sum, col_sumsq, N_NODES);
    bn_finalize_k<<<1, 128, 0, stream>>>(col_sum, col_sumsq, gP[1], bP[1], scale, shift, N_NODES);
    mgemm2_k<<<gM, 256, 0, stream>>>(ybuf, WF2_1, scale, shift, b2[1], ybuf, N_NODES);
    pool_k<<<N_GRAPHS, 256, 0, stream>>>(ybuf, gstart, out_f + 128);

    // ---- layer 2 ----
    agg_d128_k<<<(N_NODES + 7) / 8, 256, 0, stream>>>(ybuf, rowstart, adj_src, adj_ea, WeT2, be[2], hA, N_NODES);
    hipMemsetAsync(stats, 0, 2 * 128 * 4, stream);
    mgemm1_k<128><<<gM, 256, 0, stream>>>(hA, WF1_2, hA, col_sum, col_sumsq, N_NODES);
    bn_finalize_k<<<1, 128, 0, stream>>>(col_sum, col_sumsq, gP[2], bP[2], scale, shift, N_NODES);
    mgemm2_k<<<gM, 256, 0, stream>>>(hA, WF2_2, scale, shift, b2[2], hA, N_NODES);
    pool_k<<<N_GRAPHS, 256, 0, stream>>>(hA, gstart, out_f + 256);
}

// Round 4
// 494.144 us; speedup vs baseline: 2.3870x; 1.3034x over previous
//
#include <hip/hip_runtime.h>

#define N_NODES 50000
#define N_EDGES 800000
#define N_GRAPHS 500
#define DH 128
#define OUT_STRIDE 384
#define BN_EPS 1e-5f
#define SCAN_NB ((N_NODES + 255) / 256)

typedef __attribute__((ext_vector_type(8))) short bf16x8;
typedef __attribute__((ext_vector_type(4))) float f32x4;

__device__ __forceinline__ float4 ld4(const float* p) { return *(const float4*)p; }
__device__ __forceinline__ void st4(float* p, float4 v) { *(float4*)p = v; }

__device__ __forceinline__ short f2bf(float f) {
    union { float f; unsigned u; } v; v.f = f;
    unsigned r = v.u + 0x7FFFu + ((v.u >> 16) & 1u);
    return (short)(r >> 16);
}
__device__ __forceinline__ float bu2f(unsigned short v) {
    union { unsigned u; float f; } x; x.u = ((unsigned)v) << 16; return x.f;
}

// ---------------- CSR build ----------------
__global__ void count_deg_k(const int* __restrict__ dst, int* __restrict__ deg, int E) {
    int e = blockIdx.x * 256 + threadIdx.x;
    if (e < E) atomicAdd(&deg[dst[e]], 1);
}

// hierarchical scan: block sums -> scan sums -> block-local scan + offset
__global__ void deg_bsum_k(const int* __restrict__ deg, int* __restrict__ bsum, int n) {
    __shared__ int red[256];
    int t = threadIdx.x, i = blockIdx.x * 256 + t;
    red[t] = (i < n) ? deg[i] : 0;
    __syncthreads();
    for (int off = 128; off > 0; off >>= 1) {
        if (t < off) red[t] += red[t + off];
        __syncthreads();
    }
    if (t == 0) bsum[blockIdx.x] = red[0];
}

__global__ void bsum_scan_k(const int* __restrict__ bsum, int* __restrict__ boff,
                            int* __restrict__ rowstart, int nb, int n) {
    __shared__ int s[256];
    int t = threadIdx.x;
    int v = (t < nb) ? bsum[t] : 0;
    s[t] = v;
    __syncthreads();
    for (int off = 1; off < 256; off <<= 1) {
        int u = (t >= off) ? s[t - off] : 0;
        __syncthreads();
        s[t] += u;
        __syncthreads();
    }
    if (t < nb) boff[t] = s[t] - v;
    if (t == 255) rowstart[n] = s[255];
}

__global__ void deg_scan_k(const int* __restrict__ deg, const int* __restrict__ boff,
                           int* __restrict__ rowstart, int* __restrict__ cursor, int n) {
    __shared__ int s[256];
    int t = threadIdx.x, i = blockIdx.x * 256 + t;
    int v = (i < n) ? deg[i] : 0;
    s[t] = v;
    __syncthreads();
    for (int off = 1; off < 256; off <<= 1) {
        int u = (t >= off) ? s[t - off] : 0;
        __syncthreads();
        s[t] += u;
        __syncthreads();
    }
    if (i < n) {
        int r = boff[blockIdx.x] + s[t] - v;
        rowstart[i] = r;
        cursor[i] = r;
    }
}

// interleaved adjacency payload: {src(int bits), e0, e1, e2}
__global__ void csr_fill_k(const int* __restrict__ src, const int* __restrict__ dst,
                           const float* __restrict__ ea, int* __restrict__ cursor,
                           float4* __restrict__ adj, int E) {
    int e = blockIdx.x * 256 + threadIdx.x;
    if (e >= E) return;
    int pos = atomicAdd(&cursor[dst[e]], 1);
    adj[pos] = make_float4(__int_as_float(src[e]), ea[e * 3 + 0], ea[e * 3 + 1], ea[e * 3 + 2]);
}

// ---------------- graph boundaries (batch is sorted) ----------------
__global__ void graph_bounds_k(const int* __restrict__ batch, int* __restrict__ gstart, int n, int G) {
    int i = blockIdx.x * 256 + threadIdx.x;
    if (i >= n) return;
    int b = batch[i];
    if (i == 0) {
        for (int g = 0; g <= b; ++g) gstart[g] = 0;
    } else {
        int p = batch[i - 1];
        for (int g = p + 1; g <= b; ++g) gstart[g] = i;
    }
    if (i == n - 1) {
        for (int g = b + 1; g <= G; ++g) gstart[g] = n;
    }
}

// ---------------- prep: pad x to stride 12; We transposes; W -> MFMA B-frags ----------------
__global__ void pad_x_k(const float* __restrict__ x, float* __restrict__ x12, int n) {
    int i = blockIdx.x * 256 + threadIdx.x;
    if (i >= n) return;
    const float* s = x + (size_t)i * 9;
    float* d = x12 + (size_t)i * 12;
    st4(d, make_float4(s[0], s[1], s[2], s[3]));
    st4(d + 4, make_float4(s[4], s[5], s[6], s[7]));
    st4(d + 8, make_float4(s[8], 0.f, 0.f, 0.f));
}

__global__ void transposeWe_k(const float* __restrict__ A, const float* __restrict__ B,
                              float* __restrict__ TA, float* __restrict__ TB) {
    const float* in = blockIdx.y ? B : A;
    float* out = blockIdx.y ? TB : TA;
    int idx = blockIdx.x * 256 + threadIdx.x;
    if (idx < 384) {
        int r = idx / 3, c = idx - r * 3;
        out[c * 128 + r] = in[idx];
    }
}

struct WfragArgs {
    const float* W[6];
    short* WF[6];
    int din[6];
    int KP[6];
};

// chunkIdx = (nt*NC + c)*16 + n16, n = nt*16+n16, k = c*8+j, NC = KP/8
__global__ void wfrag_all_k(WfragArgs a) {
    int which = blockIdx.y;
    int din = a.din[which], KP = a.KP[which];
    const float* W = a.W[which];
    short* WF = a.WF[which];
    int NC = KP >> 3;
    int total = 8 * NC * 16;
    int idx = blockIdx.x * 256 + threadIdx.x;
    if (idx >= total) return;
    int n16 = idx & 15;
    int rest = idx >> 4;
    int c = rest % NC;
    int nt = rest / NC;
    int n = nt * 16 + n16;
    union { short s[8]; int4 v; } u;
#pragma unroll
    for (int j = 0; j < 8; ++j) {
        int k = c * 8 + j;
        float val = (k < din) ? W[(size_t)n * din + k] : 0.f;
        u.s[j] = f2bf(val);
    }
    ((int4*)WF)[idx] = u.v;
}

// ---------------- aggregation layer 0: y[n][32] = pad(x + sum relu(x[src]+Lin(ea))) ----------------
__global__ __launch_bounds__(256) void agg_d9_k(
    const float* __restrict__ x12, const int* __restrict__ rowstart,
    const float4* __restrict__ adj,
    const float* __restrict__ We /*[9][3]*/, const float* __restrict__ be,
    float* __restrict__ y /*[n][32]*/, int n) {
    int i = blockIdx.x * 256 + threadIdx.x;
    if (i >= n) return;
    float w0[9], w1[9], w2[9], bb[9], acc[9];
#pragma unroll
    for (int j = 0; j < 9; ++j) {
        w0[j] = We[j * 3 + 0];
        w1[j] = We[j * 3 + 1];
        w2[j] = We[j * 3 + 2];
        bb[j] = be[j];
    }
    {
        const float* xr = x12 + (size_t)i * 12;
#pragma unroll
        for (int j = 0; j < 9; ++j) acc[j] = xr[j];
    }
    int k1 = rowstart[i + 1];
    for (int k = rowstart[i]; k < k1; ++k) {
        float4 ed = adj[k];
        int s = __float_as_int(ed.x);
        float e0 = ed.y, e1 = ed.z, e2 = ed.w;
        const float* xr = x12 + (size_t)s * 12;
        float4 r0 = ld4(xr), r1 = ld4(xr + 4), r2 = ld4(xr + 8);
        float xv[9] = {r0.x, r0.y, r0.z, r0.w, r1.x, r1.y, r1.z, r1.w, r2.x};
#pragma unroll
        for (int j = 0; j < 9; ++j) {
            float lin = fmaf(w0[j], e0, fmaf(w1[j], e1, fmaf(w2[j], e2, bb[j])));
            acc[j] += fmaxf(xv[j] + lin, 0.f);
        }
    }
    float* yp = y + (size_t)i * 32;
#pragma unroll
    for (int j = 0; j < 9; ++j) yp[j] = acc[j];
#pragma unroll
    for (int j = 9; j < 32; ++j) yp[j] = 0.f;
}

// ---------------- aggregation d=128: acc fp32 from h; gather from bf16 copy ----------------
__global__ __launch_bounds__(256) void agg_d128_k(
    const float* __restrict__ h, const unsigned short* __restrict__ hbf,
    const int* __restrict__ rowstart, const float4* __restrict__ adj,
    const float* __restrict__ WeT /*[3][128]*/, const float* __restrict__ be,
    float* __restrict__ y, int n) {
    int lane = threadIdx.x & 31;
    int node = blockIdx.x * 8 + (threadIdx.x >> 5);
    if (node >= n) return;
    int c = lane * 4;
    float4 w0 = ld4(&WeT[0 * 128 + c]);
    float4 w1 = ld4(&WeT[1 * 128 + c]);
    float4 w2 = ld4(&WeT[2 * 128 + c]);
    float4 b4 = ld4(&be[c]);
    float4 acc = ld4(&h[(size_t)node * 128 + c]);
    const ushort4* hb = (const ushort4*)hbf;
    int k = rowstart[node];
    int k1 = rowstart[node + 1];
    for (; k + 2 <= k1; k += 2) {
        float4 eda = adj[k], edb = adj[k + 1];
        int s0 = __float_as_int(eda.x), s1 = __float_as_int(edb.x);
        ushort4 ua = hb[(size_t)s0 * 32 + lane];
        ushort4 ub = hb[(size_t)s1 * 32 + lane];
        float ax = fmaf(w0.x, eda.y, fmaf(w1.x, eda.z, fmaf(w2.x, eda.w, b4.x))) + bu2f(ua.x);
        float ay = fmaf(w0.y, eda.y, fmaf(w1.y, eda.z, fmaf(w2.y, eda.w, b4.y))) + bu2f(ua.y);
        float az = fmaf(w0.z, eda.y, fmaf(w1.z, eda.z, fmaf(w2.z, eda.w, b4.z))) + bu2f(ua.z);
        float aw = fmaf(w0.w, eda.y, fmaf(w1.w, eda.z, fmaf(w2.w, eda.w, b4.w))) + bu2f(ua.w);
        float bx = fmaf(w0.x, edb.y, fmaf(w1.x, edb.z, fmaf(w2.x, edb.w, b4.x))) + bu2f(ub.x);
        float by = fmaf(w0.y, edb.y, fmaf(w1.y, edb.z, fmaf(w2.y, edb.w, b4.y))) + bu2f(ub.y);
        float bz = fmaf(w0.z, edb.y, fmaf(w1.z, edb.z, fmaf(w2.z, edb.w, b4.z))) + bu2f(ub.z);
        float bw = fmaf(w0.w, edb.y, fmaf(w1.w, edb.z, fmaf(w2.w, edb.w, b4.w))) + bu2f(ub.w);
        acc.x += fmaxf(ax, 0.f) + fmaxf(bx, 0.f);
        acc.y += fmaxf(ay, 0.f) + fmaxf(by, 0.f);
        acc.z += fmaxf(az, 0.f) + fmaxf(bz, 0.f);
        acc.w += fmaxf(aw, 0.f) + fmaxf(bw, 0.f);
    }
    if (k < k1) {
        float4 ed = adj[k];
        int s = __float_as_int(ed.x);
        ushort4 ua = hb[(size_t)s * 32 + lane];
        float mx = fmaf(w0.x, ed.y, fmaf(w1.x, ed.z, fmaf(w2.x, ed.w, b4.x))) + bu2f(ua.x);
        float my = fmaf(w0.y, ed.y, fmaf(w1.y, ed.z, fmaf(w2.y, ed.w, b4.y))) + bu2f(ua.y);
        float mz = fmaf(w0.z, ed.y, fmaf(w1.z, ed.z, fmaf(w2.z, ed.w, b4.z))) + bu2f(ua.z);
        float mw = fmaf(w0.w, ed.y, fmaf(w1.w, ed.z, fmaf(w2.w, ed.w, b4.w))) + bu2f(ua.w);
        acc.x += fmaxf(mx, 0.f);
        acc.y += fmaxf(my, 0.f);
        acc.z += fmaxf(mz, 0.f);
        acc.w += fmaxf(mw, 0.f);
    }
    st4(&y[(size_t)node * 128 + c], acc);
}

// ---------------- A-fragment helpers ----------------
__device__ __forceinline__ bf16x8 loadA(const float* p, bool v) {
    union { short s[8]; bf16x8 v8; } u;
    if (v) {
        float4 a = ld4(p), b = ld4(p + 4);
        u.s[0] = f2bf(a.x); u.s[1] = f2bf(a.y); u.s[2] = f2bf(a.z); u.s[3] = f2bf(a.w);
        u.s[4] = f2bf(b.x); u.s[5] = f2bf(b.y); u.s[6] = f2bf(b.z); u.s[7] = f2bf(b.w);
    } else {
#pragma unroll
        for (int j = 0; j < 8; ++j) u.s[j] = 0;
    }
    return u.v8;
}

__device__ __forceinline__ bf16x8 loadA_bn(const float* p, bool v,
                                           float4 sc0, float4 sc1, float4 sh0, float4 sh1) {
    union { short s[8]; bf16x8 v8; } u;
    if (v) {
        float4 a = ld4(p), b = ld4(p + 4);
        u.s[0] = f2bf(fmaxf(fmaf(a.x, sc0.x, sh0.x), 0.f));
        u.s[1] = f2bf(fmaxf(fmaf(a.y, sc0.y, sh0.y), 0.f));
        u.s[2] = f2bf(fmaxf(fmaf(a.z, sc0.z, sh0.z), 0.f));
        u.s[3] = f2bf(fmaxf(fmaf(a.w, sc0.w, sh0.w), 0.f));
        u.s[4] = f2bf(fmaxf(fmaf(b.x, sc1.x, sh1.x), 0.f));
        u.s[5] = f2bf(fmaxf(fmaf(b.y, sc1.y, sh1.y), 0.f));
        u.s[6] = f2bf(fmaxf(fmaf(b.z, sc1.z, sh1.z), 0.f));
        u.s[7] = f2bf(fmaxf(fmaf(b.w, sc1.w, sh1.w), 0.f));
    } else {
#pragma unroll
        for (int j = 0; j < 8; ++j) u.s[j] = 0;
    }
    return u.v8;
}

// ---------------- MFMA GEMM1: H = Y @ Wt, + BN column stats ----------------
template <int KP>
__global__ __launch_bounds__(256) void mgemm1_k(
    const float* Y /* [n][KP] */, const short* __restrict__ WF,
    float* Hout /* [n][128] */, float* __restrict__ col_sum, float* __restrict__ col_sumsq, int n) {
    constexpr int NC = KP / 8;
    constexpr int KB = KP / 32;
    __shared__ short Wlds[8 * NC * 16 * 8];
    __shared__ float red[256];
    const int t = threadIdx.x;
    const int lane = t & 63, w = t >> 6;
    const int l15 = lane & 15, q = lane >> 4;
    const int row0 = blockIdx.x * 128 + w * 32;

    {
        const int4* s = (const int4*)WF;
        int4* d = (int4*)Wlds;
        for (int i = t; i < 8 * NC * 16; i += 256) d[i] = s[i];
    }
    red[t] = 0.f;
    __syncthreads();

    f32x4 acc[2][8];
#pragma unroll
    for (int rt = 0; rt < 2; ++rt)
#pragma unroll
        for (int nt = 0; nt < 8; ++nt) acc[rt][nt] = (f32x4){0.f, 0.f, 0.f, 0.f};

    const int r0 = row0 + l15, r1 = row0 + 16 + l15;
    const float* p0 = Y + (size_t)r0 * KP + q * 8;
    const float* p1 = Y + (size_t)r1 * KP + q * 8;
    const bool v0 = r0 < n, v1 = r1 < n;
    const bf16x8* WL = (const bf16x8*)Wlds;

#pragma unroll
    for (int b = 0; b < KB; ++b) {
        bf16x8 a0 = loadA(p0 + b * 32, v0);
        bf16x8 a1 = loadA(p1 + b * 32, v1);
#pragma unroll
        for (int nt = 0; nt < 8; ++nt) {
            bf16x8 bf = WL[(nt * NC + b * 4 + q) * 16 + l15];
            acc[0][nt] = __builtin_amdgcn_mfma_f32_16x16x32_bf16(a0, bf, acc[0][nt], 0, 0, 0);
            acc[1][nt] = __builtin_amdgcn_mfma_f32_16x16x32_bf16(a1, bf, acc[1][nt], 0, 0, 0);
        }
    }

#pragma unroll
    for (int nt = 0; nt < 8; ++nt) {
        float s = 0.f, ss = 0.f;
#pragma unroll
        for (int rt = 0; rt < 2; ++rt) {
            int rb = row0 + rt * 16 + q * 4;
#pragma unroll
            for (int i = 0; i < 4; ++i) {
                float d = acc[rt][nt][i];
                int r = rb + i;
                if (r < n) Hout[(size_t)r * 128 + nt * 16 + l15] = d;
                s += d;
                ss += d * d;
            }
        }
        s += __shfl_xor(s, 16);
        s += __shfl_xor(s, 32);
        ss += __shfl_xor(ss, 16);
        ss += __shfl_xor(ss, 32);
        if (lane < 16) {
            atomicAdd(&red[nt * 16 + l15], s);
            atomicAdd(&red[128 + nt * 16 + l15], ss);
        }
    }
    __syncthreads();
    if (t < 128) atomicAdd(&col_sum[t], red[t]);
    else atomicAdd(&col_sumsq[t - 128], red[t]);
}

// ---------------- BN finalize: scale/shift ----------------
__global__ void bn_finalize_k(const float* __restrict__ col_sum, const float* __restrict__ col_sumsq,
                              const float* __restrict__ g, const float* __restrict__ b,
                              float* __restrict__ scale, float* __restrict__ shift, int n) {
    int j = threadIdx.x;
    float inv_n = 1.0f / (float)n;
    float mean = col_sum[j] * inv_n;
    float var = col_sumsq[j] * inv_n - mean * mean;
    float a = g[j] * rsqrtf(var + BN_EPS);
    scale[j] = a;
    shift[j] = fmaf(-mean, a, b[j]);
}

// ---------------- MFMA GEMM2: h = relu(relu(BN(Hpre)) @ Wt + b2); fp32 + bf16 stores ----------------
__global__ __launch_bounds__(256) void mgemm2_k(
    const float* Hpre, const short* __restrict__ WF,
    const float* __restrict__ scale, const float* __restrict__ shift,
    const float* __restrict__ bias, float* Hout, unsigned short* __restrict__ Hbf, int n) {
    constexpr int NC = 16;
    __shared__ short Wlds[8 * NC * 16 * 8];
    const int t = threadIdx.x;
    const int lane = t & 63, w = t >> 6;
    const int l15 = lane & 15, q = lane >> 4;
    const int row0 = blockIdx.x * 128 + w * 32;

    {
        const int4* s = (const int4*)WF;
        int4* d = (int4*)Wlds;
        for (int i = t; i < 8 * NC * 16; i += 256) d[i] = s[i];
    }
    __syncthreads();

    f32x4 acc[2][8];
#pragma unroll
    for (int rt = 0; rt < 2; ++rt)
#pragma unroll
        for (int nt = 0; nt < 8; ++nt) acc[rt][nt] = (f32x4){0.f, 0.f, 0.f, 0.f};

    const int r0 = row0 + l15, r1 = row0 + 16 + l15;
    const float* p0 = Hpre + (size_t)r0 * 128 + q * 8;
    const float* p1 = Hpre + (size_t)r1 * 128 + q * 8;
    const bool v0 = r0 < n, v1 = r1 < n;
    const bf16x8* WL = (const bf16x8*)Wlds;

#pragma unroll
    for (int b = 0; b < 4; ++b) {
        const int k0 = b * 32 + q * 8;
        float4 sc0 = ld4(&scale[k0]), sc1 = ld4(&scale[k0 + 4]);
        float4 sh0 = ld4(&shift[k0]), sh1 = ld4(&shift[k0 + 4]);
        bf16x8 a0 = loadA_bn(p0 + b * 32, v0, sc0, sc1, sh0, sh1);
        bf16x8 a1 = loadA_bn(p1 + b * 32, v1, sc0, sc1, sh0, sh1);
#pragma unroll
        for (int nt = 0; nt < 8; ++nt) {
            bf16x8 bf = WL[(nt * NC + b * 4 + q) * 16 + l15];
            acc[0][nt] = __builtin_amdgcn_mfma_f32_16x16x32_bf16(a0, bf, acc[0][nt], 0, 0, 0);
            acc[1][nt] = __builtin_amdgcn_mfma_f32_16x16x32_bf16(a1, bf, acc[1][nt], 0, 0, 0);
        }
    }

#pragma unroll
    for (int nt = 0; nt < 8; ++nt) {
        float bcol = bias[nt * 16 + l15];
#pragma unroll
        for (int rt = 0; rt < 2; ++rt) {
            int rb = row0 + rt * 16 + q * 4;
#pragma unroll
            for (int i = 0; i < 4; ++i) {
                int r = rb + i;
                if (r < n) {
                    float o = fmaxf(acc[rt][nt][i] + bcol, 0.f);
                    Hout[(size_t)r * 128 + nt * 16 + l15] = o;
                    Hbf[(size_t)r * 128 + nt * 16 + l15] = (unsigned short)f2bf(o);
                }
            }
        }
    }
}

// ---------------- per-graph pool (exclusive ranges, no atomics) ----------------
__global__ __launch_bounds__(256) void pool_k(
    const float* __restrict__ H, const int* __restrict__ gstart,
    float* __restrict__ out /* base + layer*128 */) {
    int g = blockIdx.x;
    int t = threadIdx.x;
    int c = t & 127;
    int half = t >> 7;  // 0/1
    int r0 = gstart[g], r1 = gstart[g + 1];
    float s = 0.f;
    for (int r = r0 + half; r < r1; r += 2) s += H[(size_t)r * 128 + c];
    __shared__ float red[256];
    red[t] = s;
    __syncthreads();
    if (t < 128) out[(size_t)g * OUT_STRIDE + t] = red[t] + red[t + 128];
}

extern "C" void kernel_launch(void* const* d_in, const int* in_sizes, int n_in,
                              void* d_out, int out_size, void* d_ws, size_t ws_size,
                              hipStream_t stream) {
    const float* x = (const float*)d_in[0];
    const int* ei = (const int*)d_in[1];
    const float* ea = (const float*)d_in[2];
    const int* batch = (const int*)d_in[3];
    const int* srcArr = ei;
    const int* dstArr = ei + N_EDGES;

    const float *We[3], *be[3], *W1[3], *gP[3], *bP[3], *W2[3], *b2[3];
    for (int l = 0; l < 3; ++l) {
        int base = 4 + 7 * l;
        We[l] = (const float*)d_in[base + 0];
        be[l] = (const float*)d_in[base + 1];
        W1[l] = (const float*)d_in[base + 2];
        gP[l] = (const float*)d_in[base + 3];
        bP[l] = (const float*)d_in[base + 4];
        W2[l] = (const float*)d_in[base + 5];
        b2[l] = (const float*)d_in[base + 6];
    }

    char* w = (char*)d_ws;
    auto carve = [&](size_t bytes) {
        char* p = w;
        w += (bytes + 255) & ~(size_t)255;
        return p;
    };
    int* deg = (int*)carve((size_t)N_NODES * 4);
    int* rowstart = (int*)carve((size_t)(N_NODES + 1) * 4);
    int* cursor = (int*)carve((size_t)N_NODES * 4);
    int* bsum = (int*)carve((size_t)SCAN_NB * 4);
    int* boff = (int*)carve((size_t)SCAN_NB * 4);
    int* gstart = (int*)carve((size_t)(N_GRAPHS + 1) * 4);
    float4* adj = (float4*)carve((size_t)N_EDGES * 16);
    float* WeT1 = (float*)carve(3 * 128 * 4);
    float* WeT2 = (float*)carve(3 * 128 * 4);
    short* WF1_0 = (short*)carve(8 * 4 * 16 * 8 * 2);    // KP=32
    short* WF1_1 = (short*)carve(8 * 16 * 16 * 8 * 2);   // KP=128
    short* WF1_2 = (short*)carve(8 * 16 * 16 * 8 * 2);
    short* WF2_0 = (short*)carve(8 * 16 * 16 * 8 * 2);
    short* WF2_1 = (short*)carve(8 * 16 * 16 * 8 * 2);
    short* WF2_2 = (short*)carve(8 * 16 * 16 * 8 * 2);
    float* stats = (float*)carve(3 * 256 * 4);           // per-layer col_sum/col_sumsq
    float* scsh = (float*)carve(2 * 128 * 4);            // scale/shift (reused per layer)
    float* x12 = (float*)carve((size_t)N_NODES * 12 * 4);
    float* y0p = (float*)carve((size_t)N_NODES * 32 * 4);
    float* hA = (float*)carve((size_t)N_NODES * 128 * 4);
    float* ybuf = (float*)carve((size_t)N_NODES * 128 * 4);
    unsigned short* hbf = (unsigned short*)carve((size_t)N_NODES * 128 * 2);
    float* scale = scsh;
    float* shift = scsh + 128;

    hipMemsetAsync(deg, 0, (size_t)N_NODES * 4, stream);
    hipMemsetAsync(stats, 0, 3 * 256 * 4, stream);

    count_deg_k<<<(N_EDGES + 255) / 256, 256, 0, stream>>>(dstArr, deg, N_EDGES);
    deg_bsum_k<<<SCAN_NB, 256, 0, stream>>>(deg, bsum, N_NODES);
    bsum_scan_k<<<1, 256, 0, stream>>>(bsum, boff, rowstart, SCAN_NB, N_NODES);
    deg_scan_k<<<SCAN_NB, 256, 0, stream>>>(deg, boff, rowstart, cursor, N_NODES);
    csr_fill_k<<<(N_EDGES + 255) / 256, 256, 0, stream>>>(srcArr, dstArr, ea, cursor, adj, N_EDGES);
    graph_bounds_k<<<(N_NODES + 255) / 256, 256, 0, stream>>>(batch, gstart, N_NODES, N_GRAPHS);
    pad_x_k<<<(N_NODES + 255) / 256, 256, 0, stream>>>(x, x12, N_NODES);

    {
        dim3 g2(2, 2);
        transposeWe_k<<<g2, 256, 0, stream>>>(We[1], We[2], WeT1, WeT2);
        WfragArgs wa;
        wa.W[0] = W1[0]; wa.WF[0] = WF1_0; wa.din[0] = 9;   wa.KP[0] = 32;
        wa.W[1] = W1[1]; wa.WF[1] = WF1_1; wa.din[1] = 128; wa.KP[1] = 128;
        wa.W[2] = W1[2]; wa.WF[2] = WF1_2; wa.din[2] = 128; wa.KP[2] = 128;
        wa.W[3] = W2[0]; wa.WF[3] = WF2_0; wa.din[3] = 128; wa.KP[3] = 128;
        wa.W[4] = W2[1]; wa.WF[4] = WF2_1; wa.din[4] = 128; wa.KP[4] = 128;
        wa.W[5] = W2[2]; wa.WF[5] = WF2_2; wa.din[5] = 128; wa.KP[5] = 128;
        dim3 gw(8, 6);
        wfrag_all_k<<<gw, 256, 0, stream>>>(wa);
    }

    const int gM = (N_NODES + 127) / 128;
    float* out_f = (float*)d_out;

    // ---- layer 0 (K=32 padded from din=9) ----
    agg_d9_k<<<(N_NODES + 255) / 256, 256, 0, stream>>>(x12, rowstart, adj, We[0], be[0], y0p, N_NODES);
    mgemm1_k<32><<<gM, 256, 0, stream>>>(y0p, WF1_0, hA, stats, stats + 128, N_NODES);
    bn_finalize_k<<<1, 128, 0, stream>>>(stats, stats + 128, gP[0], bP[0], scale, shift, N_NODES);
    mgemm2_k<<<gM, 256, 0, stream>>>(hA, WF2_0, scale, shift, b2[0], hA, hbf, N_NODES);
    pool_k<<<N_GRAPHS, 256, 0, stream>>>(hA, gstart, out_f + 0);

    // ---- layer 1 ----
    agg_d128_k<<<(N_NODES + 7) / 8, 256, 0, stream>>>(hA, hbf, rowstart, adj, WeT1, be[1], ybuf, N_NODES);
    mgemm1_k<128><<<gM, 256, 0, stream>>>(ybuf, WF1_1, ybuf, stats + 256, stats + 384, N_NODES);
    bn_finalize_k<<<1, 128, 0, stream>>>(stats + 256, stats + 384, gP[1], bP[1], scale, shift, N_NODES);
    mgemm2_k<<<gM, 256, 0, stream>>>(ybuf, WF2_1, scale, shift, b2[1], ybuf, hbf, N_NODES);
    pool_k<<<N_GRAPHS, 256, 0, stream>>>(ybuf, gstart, out_f + 128);

    // ---- layer 2 ----
    agg_d128_k<<<(N_NODES + 7) / 8, 256, 0, stream>>>(ybuf, hbf, rowstart, adj, WeT2, be[2], hA, N_NODES);
    mgemm1_k<128><<<gM, 256, 0, stream>>>(hA, WF1_2, hA, stats + 512, stats + 640, N_NODES);
    bn_finalize_k<<<1, 128, 0, stream>>>(stats + 512, stats + 640, gP[2], bP[2], scale, shift, N_NODES);
    mgemm2_k<<<gM, 256, 0, stream>>>(hA, WF2_2, scale, shift, b2[2], hA, hbf, N_NODES);
    pool_k<<<N_GRAPHS, 256, 0, stream>>>(hA, gstart, out_f + 256);
}